// Round 3
// baseline (1981.907 us; speedup 1.0000x reference)
//
#include <hip/hip_runtime.h>
#include <math.h>

#define S_ 2048
#define DIM_ 2048
#define HEADS_ 16
#define KVH_ 4
#define G_ 4
#define DH_ 128
#define NW_ 255
#define NWP_ 256
#define CBS_ 16
#define CST_ 8
#define SBS_ 16
#define NSEL_ 4
#define NF_ 128
#define SW_ 64
#define QKVN_ 3072
#define HID_ 2048
#define MROWS_ 1020   // KVH_*NW_
#define SCALE_F 0.08838834764831845f

// ---------------- RMSNorm ----------------
__global__ __launch_bounds__(256) void rmsnorm_kernel(const float* __restrict__ x,
    const float* __restrict__ g, float* __restrict__ h) {
    int s = blockIdx.x, tid = threadIdx.x;
    const float* row = x + (size_t)s * DIM_;
    float ss = 0.f;
    for (int idx = tid; idx < DIM_ / 4; idx += 256) {
        float4 v = reinterpret_cast<const float4*>(row)[idx];
        ss += v.x * v.x + v.y * v.y + v.z * v.z + v.w * v.w;
    }
    __shared__ float red[256];
    red[tid] = ss; __syncthreads();
    for (int o = 128; o > 0; o >>= 1) { if (tid < o) red[tid] += red[tid + o]; __syncthreads(); }
    float scale = 1.0f / sqrtf(red[0] / (float)DIM_ + 1e-6f);
    for (int idx = tid; idx < DIM_; idx += 256)
        h[(size_t)s * DIM_ + idx] = row[idx] * scale * g[idx];
}

// ---------------- 128x128-tile fp32 GEMM, 8x8 per thread ----------------
// A: MxK row-major, B: KxN row-major. Requires K%16==0, N%128==0; M guarded.
__global__ __launch_bounds__(256) void gemm128_kernel(
    const float* __restrict__ A, const float* __restrict__ B, float* __restrict__ C,
    int M, int N, int K) {
    __shared__ float As[16][128];   // K-major: As[k][m]
    __shared__ float Bs[16][128];   // Bs[k][n]
    const int tid = threadIdx.x;
    const int bm = blockIdx.y * 128, bn = blockIdx.x * 128;
    const int tx = tid & 15, ty = tid >> 4;
    const int m0 = ty << 3, n0 = tx << 3;
    const int a_r0 = tid >> 2, a_kc = (tid & 3) << 2;
    const int b_r0 = tid >> 5, b_c = (tid & 31) << 2;
    float acc[8][8] = {};
    for (int k0 = 0; k0 < K; k0 += 16) {
        float4 av0 = make_float4(0.f, 0.f, 0.f, 0.f), av1 = av0;
        if (bm + a_r0 < M)      av0 = *reinterpret_cast<const float4*>(A + (size_t)(bm + a_r0) * K + k0 + a_kc);
        if (bm + a_r0 + 64 < M) av1 = *reinterpret_cast<const float4*>(A + (size_t)(bm + a_r0 + 64) * K + k0 + a_kc);
        float4 bv0 = *reinterpret_cast<const float4*>(B + (size_t)(k0 + b_r0) * N + bn + b_c);
        float4 bv1 = *reinterpret_cast<const float4*>(B + (size_t)(k0 + b_r0 + 8) * N + bn + b_c);
        __syncthreads();
        As[a_kc + 0][a_r0] = av0.x; As[a_kc + 1][a_r0] = av0.y;
        As[a_kc + 2][a_r0] = av0.z; As[a_kc + 3][a_r0] = av0.w;
        As[a_kc + 0][a_r0 + 64] = av1.x; As[a_kc + 1][a_r0 + 64] = av1.y;
        As[a_kc + 2][a_r0 + 64] = av1.z; As[a_kc + 3][a_r0 + 64] = av1.w;
        *reinterpret_cast<float4*>(&Bs[b_r0][b_c]) = bv0;
        *reinterpret_cast<float4*>(&Bs[b_r0 + 8][b_c]) = bv1;
        __syncthreads();
#pragma unroll
        for (int k = 0; k < 16; ++k) {
            float a[8], b[8];
            *reinterpret_cast<float4*>(&a[0]) = *reinterpret_cast<const float4*>(&As[k][m0]);
            *reinterpret_cast<float4*>(&a[4]) = *reinterpret_cast<const float4*>(&As[k][m0 + 4]);
            *reinterpret_cast<float4*>(&b[0]) = *reinterpret_cast<const float4*>(&Bs[k][n0]);
            *reinterpret_cast<float4*>(&b[4]) = *reinterpret_cast<const float4*>(&Bs[k][n0 + 4]);
#pragma unroll
            for (int i = 0; i < 8; ++i)
#pragma unroll
                for (int j = 0; j < 8; ++j) acc[i][j] += a[i] * b[j];
        }
    }
    const int row0 = bm + m0, col0 = bn + n0;
#pragma unroll
    for (int i = 0; i < 8; ++i) {
        int r = row0 + i;
        if (r < M) {
            *reinterpret_cast<float4*>(C + (size_t)r * N + col0) = *reinterpret_cast<const float4*>(&acc[i][0]);
            *reinterpret_cast<float4*>(C + (size_t)r * N + col0 + 4) = *reinterpret_cast<const float4*>(&acc[i][4]);
        }
    }
}

// ---------------- dual 128-tile GEMM with bias+relu: z=0 k-branch, z=1 v-branch ----------------
__global__ __launch_bounds__(256) void gemm128_dual_kernel(
    const float* __restrict__ Ak, const float* __restrict__ Av,
    const float* __restrict__ Bk, const float* __restrict__ Bv,
    float* __restrict__ Ck, float* __restrict__ Cv,
    const float* __restrict__ biask, const float* __restrict__ biasv,
    int M, int N, int K) {
    const int pair = blockIdx.z;
    const float* A = pair ? Av : Ak;
    const float* B = pair ? Bv : Bk;
    const float* bias = pair ? biasv : biask;
    float* C = pair ? Cv : Ck;
    __shared__ float As[16][128];
    __shared__ float Bs[16][128];
    const int tid = threadIdx.x;
    const int bm = blockIdx.y * 128, bn = blockIdx.x * 128;
    const int tx = tid & 15, ty = tid >> 4;
    const int m0 = ty << 3, n0 = tx << 3;
    const int a_r0 = tid >> 2, a_kc = (tid & 3) << 2;
    const int b_r0 = tid >> 5, b_c = (tid & 31) << 2;
    float acc[8][8] = {};
    for (int k0 = 0; k0 < K; k0 += 16) {
        float4 av0 = make_float4(0.f, 0.f, 0.f, 0.f), av1 = av0;
        if (bm + a_r0 < M)      av0 = *reinterpret_cast<const float4*>(A + (size_t)(bm + a_r0) * K + k0 + a_kc);
        if (bm + a_r0 + 64 < M) av1 = *reinterpret_cast<const float4*>(A + (size_t)(bm + a_r0 + 64) * K + k0 + a_kc);
        float4 bv0 = *reinterpret_cast<const float4*>(B + (size_t)(k0 + b_r0) * N + bn + b_c);
        float4 bv1 = *reinterpret_cast<const float4*>(B + (size_t)(k0 + b_r0 + 8) * N + bn + b_c);
        __syncthreads();
        As[a_kc + 0][a_r0] = av0.x; As[a_kc + 1][a_r0] = av0.y;
        As[a_kc + 2][a_r0] = av0.z; As[a_kc + 3][a_r0] = av0.w;
        As[a_kc + 0][a_r0 + 64] = av1.x; As[a_kc + 1][a_r0 + 64] = av1.y;
        As[a_kc + 2][a_r0 + 64] = av1.z; As[a_kc + 3][a_r0 + 64] = av1.w;
        *reinterpret_cast<float4*>(&Bs[b_r0][b_c]) = bv0;
        *reinterpret_cast<float4*>(&Bs[b_r0 + 8][b_c]) = bv1;
        __syncthreads();
#pragma unroll
        for (int k = 0; k < 16; ++k) {
            float a[8], b[8];
            *reinterpret_cast<float4*>(&a[0]) = *reinterpret_cast<const float4*>(&As[k][m0]);
            *reinterpret_cast<float4*>(&a[4]) = *reinterpret_cast<const float4*>(&As[k][m0 + 4]);
            *reinterpret_cast<float4*>(&b[0]) = *reinterpret_cast<const float4*>(&Bs[k][n0]);
            *reinterpret_cast<float4*>(&b[4]) = *reinterpret_cast<const float4*>(&Bs[k][n0 + 4]);
#pragma unroll
            for (int i = 0; i < 8; ++i)
#pragma unroll
                for (int j = 0; j < 8; ++j) acc[i][j] += a[i] * b[j];
        }
    }
    const int row0 = bm + m0, col0 = bn + n0;
    float bs[8];
    *reinterpret_cast<float4*>(&bs[0]) = *reinterpret_cast<const float4*>(bias + col0);
    *reinterpret_cast<float4*>(&bs[4]) = *reinterpret_cast<const float4*>(bias + col0 + 4);
#pragma unroll
    for (int i = 0; i < 8; ++i) {
        int r = row0 + i;
        if (r < M) {
            float o[8];
#pragma unroll
            for (int j = 0; j < 8; ++j) o[j] = fmaxf(acc[i][j] + bs[j], 0.f);
            *reinterpret_cast<float4*>(C + (size_t)r * N + col0) = *reinterpret_cast<const float4*>(&o[0]);
            *reinterpret_cast<float4*>(C + (size_t)r * N + col0 + 4) = *reinterpret_cast<const float4*>(&o[4]);
        }
    }
}

// ---------------- dual split-K w2 GEMM: 1020x128x2048, 64x64 tile ----------------
// z = pair*4 + ks; K-chunk [ks*512, ks*512+512). Writes partials (no bias).
__global__ __launch_bounds__(256) void gemm_w2sk_kernel(
    const float* __restrict__ Ak, const float* __restrict__ Av,
    const float* __restrict__ Bk, const float* __restrict__ Bv,
    float* __restrict__ part) {
    const int pair = blockIdx.z >> 2, ks = blockIdx.z & 3;
    const float* A = pair ? Av : Ak;   // 1020 x 2048
    const float* B = pair ? Bv : Bk;   // 2048 x 128
    __shared__ float As[16][64];
    __shared__ float Bs[16][64];
    const int tid = threadIdx.x;
    const int bm = blockIdx.y * 64, bn = blockIdx.x * 64;
    const int tx = tid & 15, ty = tid >> 4;
    const int ar = tid >> 2, ac = (tid & 3) << 2;
    const int br = tid >> 4, bc = (tid & 15) << 2;
    const int k_lo = ks * 512;
    float acc[4][4] = {};
    for (int k0 = k_lo; k0 < k_lo + 512; k0 += 16) {
        float4 av = make_float4(0.f, 0.f, 0.f, 0.f);
        if (bm + ar < MROWS_) av = *reinterpret_cast<const float4*>(A + (size_t)(bm + ar) * HID_ + k0 + ac);
        float4 bv = *reinterpret_cast<const float4*>(B + (size_t)(k0 + br) * DH_ + bn + bc);
        __syncthreads();
        As[ac + 0][ar] = av.x; As[ac + 1][ar] = av.y; As[ac + 2][ar] = av.z; As[ac + 3][ar] = av.w;
        *reinterpret_cast<float4*>(&Bs[br][bc]) = bv;
        __syncthreads();
#pragma unroll
        for (int k = 0; k < 16; ++k) {
            float4 a = *reinterpret_cast<const float4*>(&As[k][ty << 2]);
            float4 b = *reinterpret_cast<const float4*>(&Bs[k][tx << 2]);
            float aa[4] = {a.x, a.y, a.z, a.w};
            float bb[4] = {b.x, b.y, b.z, b.w};
#pragma unroll
            for (int i = 0; i < 4; ++i)
#pragma unroll
                for (int j = 0; j < 4; ++j) acc[i][j] += aa[i] * bb[j];
        }
    }
    const int row0 = bm + (ty << 2), col0 = bn + (tx << 2);
    float* dst = part + ((size_t)(pair * 4 + ks) * MROWS_) * DH_;
#pragma unroll
    for (int i = 0; i < 4; ++i) {
        int r = row0 + i;
        if (r < MROWS_)
            *reinterpret_cast<float4*>(dst + (size_t)r * DH_ + col0) =
                make_float4(acc[i][0], acc[i][1], acc[i][2], acc[i][3]);
    }
}

// ---------------- reduce split-K partials + bias, prepend mem row ----------------
__global__ __launch_bounds__(128) void reduce_scatter_kernel(
    const float* __restrict__ part, const float* __restrict__ mem,
    const float* __restrict__ bk, const float* __restrict__ bv,
    float* __restrict__ ckf, float* __restrict__ cvf) {
    const int r = blockIdx.x, kvh = blockIdx.y, pair = blockIdx.z, d = threadIdx.x;
    float* dst = pair ? cvf : ckf;
    float v;
    if (r == 0) {
        v = mem[(size_t)pair * KVH_ * DH_ + kvh * DH_ + d];
    } else {
        const size_t row = (size_t)kvh * NW_ + (r - 1);
        const float* p0 = part + ((size_t)pair * 4 * MROWS_ + row) * DH_ + d;
        const size_t stride = (size_t)MROWS_ * DH_;
        v = p0[0] + p0[stride] + p0[2 * stride] + p0[3 * stride];
        v += (pair ? bv[d] : bk[d]);
    }
    dst[((size_t)kvh * NWP_ + r) * DH_ + d] = v;
}

// ---------------- build compression-MLP inputs for k and v (z selects) ----------------
__global__ __launch_bounds__(256) void build_cin_kernel(const float* __restrict__ qkv,
    const float* __restrict__ k_pos, const float* __restrict__ v_pos,
    float* __restrict__ cin_k, float* __restrict__ cin_v) {
    int w = blockIdx.x, kvh = blockIdx.y, pair = blockIdx.z, tid = threadIdx.x;
    const float* posw = pair ? v_pos : k_pos;
    float* cin = pair ? cin_v : cin_k;
    const int col_off = pair ? (DIM_ + KVH_ * DH_) : DIM_;
    for (int idx = tid; idx < CBS_ * DH_; idx += 256) {
        int t = idx >> 7, d = idx & 127;
        int srow = w * CST_ + t;
        cin[((size_t)kvh * NW_ + w) * HID_ + idx] =
            qkv[(size_t)srow * QKVN_ + col_off + kvh * DH_ + d] + posw[(kvh * CBS_ + t) * DH_ + d];
    }
}

// ---------------- RoPE for q (16 heads) and k (4 heads) ----------------
__global__ __launch_bounds__(64) void rope_kernel(const float* __restrict__ qkv,
    float* __restrict__ rq, float* __restrict__ rk) {
    int s = blockIdx.x, head = blockIdx.y, i = threadIdx.x;
    float inv = 1.0f / powf(10000.0f, (float)i / 64.0f);
    float ang = (float)s * inv;
    float c = cosf(ang), sn = sinf(ang);
    const float* src; float* dst;
    if (head < HEADS_) {
        src = qkv + (size_t)s * QKVN_ + head * DH_;
        dst = rq + ((size_t)head * S_ + s) * DH_;
    } else {
        int kvh = head - HEADS_;
        src = qkv + (size_t)s * QKVN_ + DIM_ + kvh * DH_;
        dst = rk + ((size_t)kvh * S_ + s) * DH_;
    }
    float t1 = src[2 * i], t2 = src[2 * i + 1];
    dst[2 * i] = t1 * c - t2 * sn;
    dst[2 * i + 1] = t1 * sn + t2 * c;
}

// ---------------- compression attention + importance + top-k selection ----------------
__global__ __launch_bounds__(256) void compattn_kernel(
    const float* __restrict__ qkv, const float* __restrict__ ck, const float* __restrict__ cv,
    float* __restrict__ coutb, int* __restrict__ selidx, int* __restrict__ selact) {
    const int s = blockIdx.x, kvh = blockIdx.y, tid = threadIdx.x;
    __shared__ float qs[G_][DH_];
    __shared__ float kch[64][DH_ + 1];
    __shared__ float sc[G_][NWP_];
    __shared__ float impb[NWP_];
    __shared__ float bimp[NF_];
    for (int idx = tid; idx < G_ * DH_; idx += 256) {
        int g = idx >> 7, d = idx & 127;
        qs[g][d] = qkv[(size_t)s * QKVN_ + (kvh * G_ + g) * DH_ + d];
    }
    for (int ch = 0; ch < 4; ++ch) {
        __syncthreads();
        for (int idx = tid; idx < 64 * DH_; idx += 256) {
            int r = idx >> 7, d = idx & 127;
            kch[r][d] = ck[((size_t)kvh * NWP_ + ch * 64 + r) * DH_ + d];
        }
        __syncthreads();
        {
            int g = tid >> 6, j = tid & 63;
            float a = 0.f;
#pragma unroll 8
            for (int d = 0; d < DH_; ++d) a += qs[g][d] * kch[j][d];
            sc[g][ch * 64 + j] = a * SCALE_F;
        }
    }
    __syncthreads();
    const int wv = tid >> 6, ln = tid & 63;
    float m = -INFINITY;
#pragma unroll
    for (int c = 0; c < 4; ++c) {
        int j = c * 64 + ln;
        bool vis = (j == 0) || (s > (j - 1) * CST_ + CBS_ - 1);
        float v = vis ? sc[wv][j] : -INFINITY;
        sc[wv][j] = v;
        m = fmaxf(m, v);
    }
#pragma unroll
    for (int off = 32; off > 0; off >>= 1) m = fmaxf(m, __shfl_xor(m, off));
    float ssum = 0.f, ev[4];
#pragma unroll
    for (int c = 0; c < 4; ++c) {
        float e = expf(sc[wv][c * 64 + ln] - m);
        ev[c] = e; ssum += e;
    }
#pragma unroll
    for (int off = 32; off > 0; off >>= 1) ssum += __shfl_xor(ssum, off);
    float inv = 1.f / ssum;
#pragma unroll
    for (int c = 0; c < 4; ++c) sc[wv][c * 64 + ln] = ev[c] * inv;
    __syncthreads();
    for (int j = tid; j < NWP_; j += 256)
        impb[j] = (sc[0][j] + sc[1][j] + sc[2][j] + sc[3][j]) * 0.25f;
    __syncthreads();
    if (tid < NF_) {
        float a = impb[2 * tid + 1];
        float b2 = (tid < NF_ - 1) ? impb[2 * tid + 2] : 0.f;
        float v = (a + b2) * 0.5f;
        bimp[tid] = (tid < (s >> 4)) ? v : -1.0f;
    }
    __syncthreads();
    if (tid == 0) {
        int base = (kvh * S_ + s) * NSEL_;
        for (int kk = 0; kk < NSEL_; ++kk) {
            float best = -1e30f; int bi = 0;
            for (int f = 0; f < NF_; ++f) {
                float v = bimp[f];
                if (v > best) { best = v; bi = f; }
            }
            bimp[bi] = -1e31f;
            selidx[base + kk] = bi;
            selact[base + kk] = (best > 0.f) ? 1 : 0;
        }
    }
    for (int it = tid; it < G_ * DH_; it += 256) {
        int g = it >> 7, d = it & 127;
        float a = 0.f;
        for (int j = 0; j < NWP_; ++j) a += sc[g][j] * cv[((size_t)kvh * NWP_ + j) * DH_ + d];
        coutb[(((size_t)(kvh * G_ + g)) * S_ + s) * DH_ + d] = a;
    }
}

// ---------------- selection attention (J = 80 keys) ----------------
__global__ __launch_bounds__(256) void selattn_kernel(
    const float* __restrict__ rq, const float* __restrict__ rk, const float* __restrict__ qkv,
    const int* __restrict__ selidx, const int* __restrict__ selact, float* __restrict__ foutb) {
    const int s = blockIdx.x, kvh = blockIdx.y, tid = threadIdx.x;
    const int J = (NSEL_ + 1) * SBS_;  // 80
    __shared__ float qs[G_][DH_];
    __shared__ float kl[80][DH_ + 1];
    __shared__ float sc[G_][80];
    __shared__ int posb[80];
    __shared__ int maskb[80];
    if (tid < J) {
        int b = tid >> 4, t = tid & 15;
        int p, ok;
        if (b < NSEL_) {
            int base = (kvh * S_ + s) * NSEL_ + b;
            int f = selidx[base];
            p = f * SBS_ + t;
            ok = selact[base] && (p <= s);
        } else {
            p = (s >> 4) * SBS_ + t;
            ok = (p <= s);
        }
        posb[tid] = p; maskb[tid] = ok;
    }
    for (int idx = tid; idx < G_ * DH_; idx += 256) {
        int g = idx >> 7, d = idx & 127;
        qs[g][d] = rq[(((size_t)(kvh * G_ + g)) * S_ + s) * DH_ + d];
    }
    __syncthreads();
    for (int idx = tid; idx < J * DH_; idx += 256) {
        int r = idx >> 7, d = idx & 127;
        kl[r][d] = rk[((size_t)kvh * S_ + posb[r]) * DH_ + d];
    }
    __syncthreads();
    for (int it = tid; it < G_ * J; it += 256) {
        int g = it / J, j = it % J;
        float a = 0.f;
#pragma unroll 8
        for (int d = 0; d < DH_; ++d) a += qs[g][d] * kl[j][d];
        sc[g][j] = maskb[j] ? a * SCALE_F : -INFINITY;
    }
    __syncthreads();
    const int wv = tid >> 6, ln = tid & 63;
    float v0 = sc[wv][ln];
    float v1 = (ln < J - 64) ? sc[wv][64 + ln] : -INFINITY;
    float m = fmaxf(v0, v1);
#pragma unroll
    for (int off = 32; off > 0; off >>= 1) m = fmaxf(m, __shfl_xor(m, off));
    float e0 = expf(v0 - m);
    float e1 = (ln < J - 64) ? expf(v1 - m) : 0.f;
    float ssum = e0 + e1;
#pragma unroll
    for (int off = 32; off > 0; off >>= 1) ssum += __shfl_xor(ssum, off);
    float inv = 1.f / ssum;
    sc[wv][ln] = e0 * inv;
    if (ln < J - 64) sc[wv][64 + ln] = e1 * inv;
    __syncthreads();
    for (int it = tid; it < G_ * DH_; it += 256) {
        int g = it >> 7, d = it & 127;
        float a = 0.f;
        for (int j = 0; j < J; ++j)
            a += sc[g][j] * qkv[(size_t)posb[j] * QKVN_ + (DIM_ + KVH_ * DH_) + kvh * DH_ + d];
        foutb[(((size_t)(kvh * G_ + g)) * S_ + s) * DH_ + d] = a;
    }
}

// ---------------- sliding window attention (J = 65 keys: positions s-64..s) ----------------
__global__ __launch_bounds__(256) void swattn_kernel(
    const float* __restrict__ rq, const float* __restrict__ rk, const float* __restrict__ qkv,
    float* __restrict__ swoutb) {
    const int s = blockIdx.x, kvh = blockIdx.y, tid = threadIdx.x;
    const int J = SW_ + 1;  // 65
    __shared__ float qs[G_][DH_];
    __shared__ float kl[65][DH_ + 1];
    __shared__ float sc[G_][65];
    for (int idx = tid; idx < G_ * DH_; idx += 256) {
        int g = idx >> 7, d = idx & 127;
        qs[g][d] = rq[(((size_t)(kvh * G_ + g)) * S_ + s) * DH_ + d];
    }
    for (int idx = tid; idx < J * DH_; idx += 256) {
        int r = idx >> 7, d = idx & 127;
        int p = s - SW_ + r;
        kl[r][d] = (p >= 0) ? rk[((size_t)kvh * S_ + p) * DH_ + d] : 0.f;
    }
    __syncthreads();
    for (int it = tid; it < G_ * J; it += 256) {
        int g = it / J, j = it % J;
        int p = s - SW_ + j;
        float a = 0.f;
#pragma unroll 8
        for (int d = 0; d < DH_; ++d) a += qs[g][d] * kl[j][d];
        sc[g][j] = (p >= 0) ? a * SCALE_F : -INFINITY;
    }
    __syncthreads();
    const int wv = tid >> 6, ln = tid & 63;
    float v0 = sc[wv][ln];
    float v1 = (ln < J - 64) ? sc[wv][64 + ln] : -INFINITY;
    float m = fmaxf(v0, v1);
#pragma unroll
    for (int off = 32; off > 0; off >>= 1) m = fmaxf(m, __shfl_xor(m, off));
    float e0 = expf(v0 - m);
    float e1 = (ln < J - 64) ? expf(v1 - m) : 0.f;
    float ssum = e0 + e1;
#pragma unroll
    for (int off = 32; off > 0; off >>= 1) ssum += __shfl_xor(ssum, off);
    float inv = 1.f / ssum;
    sc[wv][ln] = e0 * inv;
    if (ln < J - 64) sc[wv][64 + ln] = e1 * inv;
    __syncthreads();
    for (int it = tid; it < G_ * DH_; it += 256) {
        int g = it >> 7, d = it & 127;
        float a = 0.f;
        for (int j = 0; j < J; ++j) {
            int p = s - SW_ + j;
            int pc = p < 0 ? 0 : p;
            a += sc[g][j] * qkv[(size_t)pc * QKVN_ + (DIM_ + KVH_ * DH_) + kvh * DH_ + d];
        }
        swoutb[(((size_t)(kvh * G_ + g)) * S_ + s) * DH_ + d] = a;
    }
}

// ---------------- gating head: comb = sigmoid(h @ w_comb + b_comb) ----------------
__global__ __launch_bounds__(256) void comb_kernel(const float* __restrict__ h,
    const float* __restrict__ w_comb, const float* __restrict__ b_comb, float* __restrict__ comb) {
    int s = blockIdx.x, tid = threadIdx.x;
    __shared__ float hrow[DIM_];
    for (int idx = tid; idx < DIM_; idx += 256) hrow[idx] = h[(size_t)s * DIM_ + idx];
    __syncthreads();
    if (tid < 192) {
        int o = tid >> 2, p = tid & 3;
        float a = 0.f;
        for (int d = p; d < DIM_; d += 4) a += hrow[d] * w_comb[(size_t)d * 48 + o];
        a += __shfl_xor(a, 1);
        a += __shfl_xor(a, 2);
        if (p == 0) comb[(size_t)s * 48 + o] = 1.f / (1.f + expf(-(a + b_comb[o])));
    }
}

// ---------------- combine the three branches with gates ----------------
__global__ __launch_bounds__(256) void combine_kernel(const float* __restrict__ c0b,
    const float* __restrict__ c1b, const float* __restrict__ c2b,
    const float* __restrict__ comb, float* __restrict__ outc) {
    size_t i = (size_t)blockIdx.x * 256 + threadIdx.x;
    int s = (int)(i >> 11);
    int hd = (int)(i & 2047);
    int hh = hd >> 7;
    int d = hd & 127;
    size_t src = ((size_t)hh * S_ + s) * DH_ + d;
    const float* cb = comb + (size_t)s * 48 + hh * 3;
    outc[i] = c0b[src] * cb[0] + c1b[src] * cb[1] + c2b[src] * cb[2];
}

extern "C" void kernel_launch(void* const* d_in, const int* in_sizes, int n_in,
                              void* d_out, int out_size, void* d_ws, size_t ws_size,
                              hipStream_t stream) {
    const float* x      = (const float*)d_in[0];
    const float* g_norm = (const float*)d_in[1];
    const float* w_qkv  = (const float*)d_in[2];
    const float* k_pos  = (const float*)d_in[3];
    const float* v_pos  = (const float*)d_in[4];
    const float* mem_kv = (const float*)d_in[5];
    const float* kc_w1  = (const float*)d_in[6];
    const float* kc_b1  = (const float*)d_in[7];
    const float* kc_w2  = (const float*)d_in[8];
    const float* kc_b2  = (const float*)d_in[9];
    const float* vc_w1  = (const float*)d_in[10];
    const float* vc_b1  = (const float*)d_in[11];
    const float* vc_w2  = (const float*)d_in[12];
    const float* vc_b2  = (const float*)d_in[13];
    const float* w_comb = (const float*)d_in[14];
    const float* b_comb = (const float*)d_in[15];
    const float* w_out  = (const float*)d_in[16];
    float* out = (float*)d_out;
    float* ws = (float*)d_ws;

    // Persistent region
    float* h    = ws;                 // 4,194,304
    float* qkv  = h + 4194304;        // 6,291,456
    float* ckf  = qkv + 6291456;      // 131,072
    float* cvf  = ckf + 131072;       // 131,072
    float* base = cvf + 131072;       // union region
    // Region A (compress scratch; dead after reduce_scatter): 9,400,320 floats
    float* cin_k  = base;             // 2,088,960 (1020 x 2048)
    float* cin_v  = cin_k + 2088960;
    float* chid_k = cin_v + 2088960;
    float* chid_v = chid_k + 2088960;
    float* part   = chid_v + 2088960; // 1,044,480 (2 x 4 x 1020 x 128)
    // Region B (attention; written after Region A is dead): 22,118,400 floats
    float* rq       = base;              // 4,194,304
    float* rk       = rq + 4194304;      // 1,048,576
    float* coutb    = rk + 1048576;      // 4,194,304
    float* foutb    = coutb + 4194304;   // 4,194,304
    float* swoutb   = foutb + 4194304;   // 4,194,304
    float* combb    = swoutb + 4194304;  // 98,304
    float* combined = combb + 98304;     // 4,194,304
    int* selidx = (int*)(base + 22118400);  // 32,768 ints
    int* selact = selidx + 32768;           // 32,768 ints

    // 1) RMSNorm
    rmsnorm_kernel<<<S_, 256, 0, stream>>>(x, g_norm, h);
    // 2) qkv projection (2048x3072x2048) — 384 blocks
    gemm128_kernel<<<dim3(QKVN_ / 128, S_ / 128), 256, 0, stream>>>(h, w_qkv, qkv, S_, QKVN_, DIM_);
    // 3) compression MLPs, k+v batched
    build_cin_kernel<<<dim3(NW_, KVH_, 2), 256, 0, stream>>>(qkv, k_pos, v_pos, cin_k, cin_v);
    // w1: 1020x2048x2048 (relu+bias), dual -> 256 blocks
    gemm128_dual_kernel<<<dim3(HID_ / 128, 8, 2), 256, 0, stream>>>(
        cin_k, cin_v, kc_w1, vc_w1, chid_k, chid_v, kc_b1, vc_b1, MROWS_, HID_, HID_);
    // w2: 1020x128x2048, dual + split-K(4) -> 256 blocks
    gemm_w2sk_kernel<<<dim3(DH_ / 64, 16, 8), 256, 0, stream>>>(chid_k, chid_v, kc_w2, vc_w2, part);
    // reduce partials + bias, prepend mem rows
    reduce_scatter_kernel<<<dim3(NWP_, KVH_, 2), 128, 0, stream>>>(part, mem_kv, kc_b2, vc_b2, ckf, cvf);
    // 5) RoPE (overwrites Region A — compress scratch is dead now)
    rope_kernel<<<dim3(S_, HEADS_ + KVH_), 64, 0, stream>>>(qkv, rq, rk);
    // 6) attention branches
    compattn_kernel<<<dim3(S_, KVH_), 256, 0, stream>>>(qkv, ckf, cvf, coutb, selidx, selact);
    selattn_kernel<<<dim3(S_, KVH_), 256, 0, stream>>>(rq, rk, qkv, selidx, selact, foutb);
    swattn_kernel<<<dim3(S_, KVH_), 256, 0, stream>>>(rq, rk, qkv, swoutb);
    // 7) gating + combine
    comb_kernel<<<S_, 256, 0, stream>>>(h, w_comb, b_comb, combb);
    combine_kernel<<<(S_ * DIM_) / 256, 256, 0, stream>>>(coutb, foutb, swoutb, combb, combined);
    // 8) output projection (2048x2048x2048) — 256 blocks
    gemm128_kernel<<<dim3(DIM_ / 128, S_ / 128), 256, 0, stream>>>(combined, w_out, out, S_, DIM_, DIM_);
}

// Round 5
// 1382.209 us; speedup vs baseline: 1.4339x; 1.4339x over previous
//
#include <hip/hip_runtime.h>
#include <math.h>

#define S_ 2048
#define DIM_ 2048
#define HEADS_ 16
#define KVH_ 4
#define G_ 4
#define DH_ 128
#define NW_ 255
#define NWP_ 256
#define CBS_ 16
#define CST_ 8
#define SBS_ 16
#define NSEL_ 4
#define NF_ 128
#define SW_ 64
#define QKVN_ 3072
#define HID_ 2048
#define MROWS_ 1020   // KVH_*NW_
#define SCALE_F 0.08838834764831845f

typedef unsigned short u16;
typedef u16 u16x8 __attribute__((ext_vector_type(8)));
typedef short bf16x8 __attribute__((ext_vector_type(8)));
typedef float f32x4 __attribute__((ext_vector_type(4)));

__device__ __forceinline__ u16 f2bf(float x) {
    unsigned int u = __float_as_uint(x);
    u += 0x7fffu + ((u >> 16) & 1u);
    return (u16)(u >> 16);
}
__device__ __forceinline__ float bf2f(u16 b) {
    return __uint_as_float(((unsigned int)b) << 16);
}

// ---------------- RMSNorm (+ bf16 hi/lo split of h) ----------------
__global__ __launch_bounds__(256) void rmsnorm_kernel(const float* __restrict__ x,
    const float* __restrict__ g, float* __restrict__ h,
    u16* __restrict__ h_hi, u16* __restrict__ h_lo) {
    int s = blockIdx.x, tid = threadIdx.x;
    const float* row = x + (size_t)s * DIM_;
    float ss = 0.f;
    for (int idx = tid; idx < DIM_ / 4; idx += 256) {
        float4 v = reinterpret_cast<const float4*>(row)[idx];
        ss += v.x * v.x + v.y * v.y + v.z * v.z + v.w * v.w;
    }
    __shared__ float red[256];
    red[tid] = ss; __syncthreads();
    for (int o = 128; o > 0; o >>= 1) { if (tid < o) red[tid] += red[tid + o]; __syncthreads(); }
    float scale = 1.0f / sqrtf(red[0] / (float)DIM_ + 1e-6f);
    for (int idx = tid; idx < DIM_; idx += 256) {
        float v = row[idx] * scale * g[idx];
        size_t o = (size_t)s * DIM_ + idx;
        h[o] = v;
        u16 hb = f2bf(v);
        h_hi[o] = hb;
        h_lo[o] = f2bf(v - bf2f(hb));
    }
}

// ---------------- transpose + bf16 hi/lo split: W[K][N] -> Th/Tl[N][K] ----------------
__global__ __launch_bounds__(256) void tsplit_kernel(const float* __restrict__ W,
    u16* __restrict__ Th, u16* __restrict__ Tl, int K, int N) {
    __shared__ float t[32][33];
    int n0 = blockIdx.x * 32, k0 = blockIdx.y * 32;
    int tx = threadIdx.x & 31, ty = threadIdx.x >> 5;  // 32 x 8
#pragma unroll
    for (int j = 0; j < 4; ++j)
        t[ty + j * 8][tx] = W[(size_t)(k0 + ty + j * 8) * N + n0 + tx];
    __syncthreads();
#pragma unroll
    for (int j = 0; j < 4; ++j) {
        float v = t[tx][ty + j * 8];   // k = k0+tx, n = n0+ty+j*8
        u16 hb = f2bf(v);
        size_t o = (size_t)(n0 + ty + j * 8) * K + k0 + tx;
        Th[o] = hb;
        Tl[o] = f2bf(v - bf2f(hb));
    }
}

// ---------------- bf16x3 MFMA GEMM: C = act(Ah+Al)@(Bh+Bl)^T_layout + bias ----------------
// A (hi/lo): M x K row-major bf16. B (hi/lo): N x K row-major bf16 (pre-transposed).
// 128x128 tile, BK=32, 4 waves, each wave 64x64 via 4x4 frags of 16x16x32.
// blockIdx.z selects operand set (dual-batch). K%32==0, N%128==0; M guarded.
__global__ __launch_bounds__(256, 2) void gemm_mfma_kernel(
    const u16* __restrict__ Ah0, const u16* __restrict__ Al0,
    const u16* __restrict__ Bh0, const u16* __restrict__ Bl0,
    float* __restrict__ C0, const float* __restrict__ bias0,
    const u16* __restrict__ Ah1, const u16* __restrict__ Al1,
    const u16* __restrict__ Bh1, const u16* __restrict__ Bl1,
    float* __restrict__ C1, const float* __restrict__ bias1,
    int M, int N, int K, int act) {
    const int pair = blockIdx.z;
    const u16* Ah = pair ? Ah1 : Ah0;
    const u16* Al = pair ? Al1 : Al0;
    const u16* Bh = pair ? Bh1 : Bh0;
    const u16* Bl = pair ? Bl1 : Bl0;
    float* C = pair ? C1 : C0;
    const float* bias = pair ? bias1 : bias0;

    // stride 56 u16 = 112 B: 16B-aligned rows, 2-way max bank aliasing (free)
    __shared__ u16 sAh[128][56], sAl[128][56], sBh[128][56], sBl[128][56];
    const int tid = threadIdx.x;
    const int bm = blockIdx.y * 128, bn = blockIdx.x * 128;
    const int s0r = tid >> 2, sc = (tid & 3) * 8;   // staging: row, k-offset (8 bf16)
    const int s1r = s0r + 64;
    const int lane = tid & 63;
    const int wv = tid >> 6;
    const int wm = (wv >> 1) * 64, wn = (wv & 1) * 64;
    const int fr = lane & 15;          // row (A) / col (B) within 16-frag
    const int fk = (lane >> 4) * 8;    // k offset within 32

    f32x4 acc[4][4];
#pragma unroll
    for (int i = 0; i < 4; ++i)
#pragma unroll
        for (int j = 0; j < 4; ++j) acc[i][j] = (f32x4){0.f, 0.f, 0.f, 0.f};

    const u16x8 zz = {0, 0, 0, 0, 0, 0, 0, 0};
    for (int k0 = 0; k0 < K; k0 += 32) {
        const bool g0 = (bm + s0r) < M, g1 = (bm + s1r) < M;
        const size_t a0 = (size_t)(bm + s0r) * K + k0 + sc;
        const size_t a1 = (size_t)(bm + s1r) * K + k0 + sc;
        const size_t b0 = (size_t)(bn + s0r) * K + k0 + sc;
        const size_t b1 = (size_t)(bn + s1r) * K + k0 + sc;
        u16x8 a0h = g0 ? *(const u16x8*)(Ah + a0) : zz;
        u16x8 a0l = g0 ? *(const u16x8*)(Al + a0) : zz;
        u16x8 a1h = g1 ? *(const u16x8*)(Ah + a1) : zz;
        u16x8 a1l = g1 ? *(const u16x8*)(Al + a1) : zz;
        u16x8 b0h = *(const u16x8*)(Bh + b0);
        u16x8 b0l = *(const u16x8*)(Bl + b0);
        u16x8 b1h = *(const u16x8*)(Bh + b1);
        u16x8 b1l = *(const u16x8*)(Bl + b1);
        __syncthreads();
        *(u16x8*)&sAh[s0r][sc] = a0h; *(u16x8*)&sAl[s0r][sc] = a0l;
        *(u16x8*)&sAh[s1r][sc] = a1h; *(u16x8*)&sAl[s1r][sc] = a1l;
        *(u16x8*)&sBh[s0r][sc] = b0h; *(u16x8*)&sBl[s0r][sc] = b0l;
        *(u16x8*)&sBh[s1r][sc] = b1h; *(u16x8*)&sBl[s1r][sc] = b1l;
        __syncthreads();
        bf16x8 ah[4], al[4], bh[4], bl[4];
#pragma unroll
        for (int i = 0; i < 4; ++i) {
            ah[i] = *(const bf16x8*)&sAh[wm + i * 16 + fr][fk];
            al[i] = *(const bf16x8*)&sAl[wm + i * 16 + fr][fk];
            bh[i] = *(const bf16x8*)&sBh[wn + i * 16 + fr][fk];
            bl[i] = *(const bf16x8*)&sBl[wn + i * 16 + fr][fk];
        }
#pragma unroll
        for (int i = 0; i < 4; ++i)
#pragma unroll
            for (int j = 0; j < 4; ++j) {
                acc[i][j] = __builtin_amdgcn_mfma_f32_16x16x32_bf16(ah[i], bh[j], acc[i][j], 0, 0, 0);
                acc[i][j] = __builtin_amdgcn_mfma_f32_16x16x32_bf16(ah[i], bl[j], acc[i][j], 0, 0, 0);
                acc[i][j] = __builtin_amdgcn_mfma_f32_16x16x32_bf16(al[i], bh[j], acc[i][j], 0, 0, 0);
            }
    }
    const int rq4 = (lane >> 4) * 4;
#pragma unroll
    for (int i = 0; i < 4; ++i) {
        const int rbase = bm + wm + i * 16 + rq4;
#pragma unroll
        for (int j = 0; j < 4; ++j) {
            const int col = bn + wn + j * 16 + fr;
            const float bv = bias ? bias[col] : 0.f;
#pragma unroll
            for (int r = 0; r < 4; ++r) {
                const int row = rbase + r;
                if (row < M) {
                    float v = acc[i][j][r] + bv;
                    if (act == 1) v = fmaxf(v, 0.f);
                    C[(size_t)row * N + col] = v;
                }
            }
        }
    }
}

// ---------------- dual split-K w2 GEMM (fp32): 1020x128x2048, 64x64 tile ----------------
__global__ __launch_bounds__(256) void gemm_w2sk_kernel(
    const float* __restrict__ Ak, const float* __restrict__ Av,
    const float* __restrict__ Bk, const float* __restrict__ Bv,
    float* __restrict__ part) {
    const int pair = blockIdx.z >> 2, ks = blockIdx.z & 3;
    const float* A = pair ? Av : Ak;   // 1020 x 2048
    const float* B = pair ? Bv : Bk;   // 2048 x 128
    __shared__ float As[16][64];
    __shared__ float Bs[16][64];
    const int tid = threadIdx.x;
    const int bm = blockIdx.y * 64, bn = blockIdx.x * 64;
    const int tx = tid & 15, ty = tid >> 4;
    const int ar = tid >> 2, ac = (tid & 3) << 2;
    const int br = tid >> 4, bc = (tid & 15) << 2;
    const int k_lo = ks * 512;
    float acc[4][4] = {};
    for (int k0 = k_lo; k0 < k_lo + 512; k0 += 16) {
        float4 av = make_float4(0.f, 0.f, 0.f, 0.f);
        if (bm + ar < MROWS_) av = *reinterpret_cast<const float4*>(A + (size_t)(bm + ar) * HID_ + k0 + ac);
        float4 bv = *reinterpret_cast<const float4*>(B + (size_t)(k0 + br) * DH_ + bn + bc);
        __syncthreads();
        As[ac + 0][ar] = av.x; As[ac + 1][ar] = av.y; As[ac + 2][ar] = av.z; As[ac + 3][ar] = av.w;
        *reinterpret_cast<float4*>(&Bs[br][bc]) = bv;
        __syncthreads();
#pragma unroll
        for (int k = 0; k < 16; ++k) {
            float4 a = *reinterpret_cast<const float4*>(&As[k][ty << 2]);
            float4 b = *reinterpret_cast<const float4*>(&Bs[k][tx << 2]);
            float aa[4] = {a.x, a.y, a.z, a.w};
            float bb[4] = {b.x, b.y, b.z, b.w};
#pragma unroll
            for (int i = 0; i < 4; ++i)
#pragma unroll
                for (int j = 0; j < 4; ++j) acc[i][j] += aa[i] * bb[j];
        }
        __syncthreads();
    }
    const int row0 = bm + (ty << 2), col0 = bn + (tx << 2);
    float* dst = part + ((size_t)(pair * 4 + ks) * MROWS_) * DH_;
#pragma unroll
    for (int i = 0; i < 4; ++i) {
        int r = row0 + i;
        if (r < MROWS_)
            *reinterpret_cast<float4*>(dst + (size_t)r * DH_ + col0) =
                make_float4(acc[i][0], acc[i][1], acc[i][2], acc[i][3]);
    }
}

// ---------------- reduce split-K partials + bias, prepend mem row ----------------
__global__ __launch_bounds__(128) void reduce_scatter_kernel(
    const float* __restrict__ part, const float* __restrict__ mem,
    const float* __restrict__ bk, const float* __restrict__ bv,
    float* __restrict__ ckf, float* __restrict__ cvf) {
    const int r = blockIdx.x, kvh = blockIdx.y, pair = blockIdx.z, d = threadIdx.x;
    float* dst = pair ? cvf : ckf;
    float v;
    if (r == 0) {
        v = mem[(size_t)pair * KVH_ * DH_ + kvh * DH_ + d];
    } else {
        const size_t row = (size_t)kvh * NW_ + (r - 1);
        const float* p0 = part + ((size_t)pair * 4 * MROWS_ + row) * DH_ + d;
        const size_t stride = (size_t)MROWS_ * DH_;
        v = p0[0] + p0[stride] + p0[2 * stride] + p0[3 * stride];
        v += (pair ? bv[d] : bk[d]);
    }
    dst[((size_t)kvh * NWP_ + r) * DH_ + d] = v;
}

// ---------------- build compression-MLP inputs (bf16 hi/lo), k and v ----------------
__global__ __launch_bounds__(256) void build_cin_kernel(const float* __restrict__ qkv,
    const float* __restrict__ k_pos, const float* __restrict__ v_pos,
    u16* __restrict__ cink_h, u16* __restrict__ cink_l,
    u16* __restrict__ cinv_h, u16* __restrict__ cinv_l) {
    int w = blockIdx.x, kvh = blockIdx.y, pair = blockIdx.z, tid = threadIdx.x;
    const float* posw = pair ? v_pos : k_pos;
    u16* ch = pair ? cinv_h : cink_h;
    u16* cl = pair ? cinv_l : cink_l;
    const int col_off = pair ? (DIM_ + KVH_ * DH_) : DIM_;
    for (int idx = tid; idx < CBS_ * DH_; idx += 256) {
        int t = idx >> 7, d = idx & 127;
        int srow = w * CST_ + t;
        float v = qkv[(size_t)srow * QKVN_ + col_off + kvh * DH_ + d] + posw[(kvh * CBS_ + t) * DH_ + d];
        size_t o = ((size_t)kvh * NW_ + w) * HID_ + idx;
        u16 hb = f2bf(v);
        ch[o] = hb;
        cl[o] = f2bf(v - bf2f(hb));
    }
}

// ---------------- RoPE for q (16 heads) and k (4 heads) ----------------
__global__ __launch_bounds__(64) void rope_kernel(const float* __restrict__ qkv,
    float* __restrict__ rq, float* __restrict__ rk) {
    int s = blockIdx.x, head = blockIdx.y, i = threadIdx.x;
    float inv = 1.0f / powf(10000.0f, (float)i / 64.0f);
    float ang = (float)s * inv;
    float c = cosf(ang), sn = sinf(ang);
    const float* src; float* dst;
    if (head < HEADS_) {
        src = qkv + (size_t)s * QKVN_ + head * DH_;
        dst = rq + ((size_t)head * S_ + s) * DH_;
    } else {
        int kvh = head - HEADS_;
        src = qkv + (size_t)s * QKVN_ + DIM_ + kvh * DH_;
        dst = rk + ((size_t)kvh * S_ + s) * DH_;
    }
    float t1 = src[2 * i], t2 = src[2 * i + 1];
    dst[2 * i] = t1 * c - t2 * sn;
    dst[2 * i + 1] = t1 * sn + t2 * c;
}

// ---------------- compression attention + importance + top-k selection ----------------
__global__ __launch_bounds__(256) void compattn_kernel(
    const float* __restrict__ qkv, const float* __restrict__ ck, const float* __restrict__ cv,
    float* __restrict__ coutb, int* __restrict__ selidx, int* __restrict__ selact) {
    const int s = blockIdx.x, kvh = blockIdx.y, tid = threadIdx.x;
    __shared__ float qs[G_][DH_];
    __shared__ float kch[64][DH_ + 1];
    __shared__ float sc[G_][NWP_];
    __shared__ float impb[NWP_];
    __shared__ float bimp[NF_];
    for (int idx = tid; idx < G_ * DH_; idx += 256) {
        int g = idx >> 7, d = idx & 127;
        qs[g][d] = qkv[(size_t)s * QKVN_ + (kvh * G_ + g) * DH_ + d];
    }
    for (int ch = 0; ch < 4; ++ch) {
        __syncthreads();
        for (int idx = tid; idx < 64 * DH_; idx += 256) {
            int r = idx >> 7, d = idx & 127;
            kch[r][d] = ck[((size_t)kvh * NWP_ + ch * 64 + r) * DH_ + d];
        }
        __syncthreads();
        {
            int g = tid >> 6, j = tid & 63;
            float a = 0.f;
#pragma unroll 8
            for (int d = 0; d < DH_; ++d) a += qs[g][d] * kch[j][d];
            sc[g][ch * 64 + j] = a * SCALE_F;
        }
    }
    __syncthreads();
    const int wv = tid >> 6, ln = tid & 63;
    float m = -INFINITY;
#pragma unroll
    for (int c = 0; c < 4; ++c) {
        int j = c * 64 + ln;
        bool vis = (j == 0) || (s > (j - 1) * CST_ + CBS_ - 1);
        float v = vis ? sc[wv][j] : -INFINITY;
        sc[wv][j] = v;
        m = fmaxf(m, v);
    }
#pragma unroll
    for (int off = 32; off > 0; off >>= 1) m = fmaxf(m, __shfl_xor(m, off));
    float ssum = 0.f, ev[4];
#pragma unroll
    for (int c = 0; c < 4; ++c) {
        float e = expf(sc[wv][c * 64 + ln] - m);
        ev[c] = e; ssum += e;
    }
#pragma unroll
    for (int off = 32; off > 0; off >>= 1) ssum += __shfl_xor(ssum, off);
    float inv = 1.f / ssum;
#pragma unroll
    for (int c = 0; c < 4; ++c) sc[wv][c * 64 + ln] = ev[c] * inv;
    __syncthreads();
    for (int j = tid; j < NWP_; j += 256)
        impb[j] = (sc[0][j] + sc[1][j] + sc[2][j] + sc[3][j]) * 0.25f;
    __syncthreads();
    if (tid < NF_) {
        float a = impb[2 * tid + 1];
        float b2 = (tid < NF_ - 1) ? impb[2 * tid + 2] : 0.f;
        float v = (a + b2) * 0.5f;
        bimp[tid] = (tid < (s >> 4)) ? v : -1.0f;
    }
    __syncthreads();
    if (tid == 0) {
        int base = (kvh * S_ + s) * NSEL_;
        for (int kk = 0; kk < NSEL_; ++kk) {
            float best = -1e30f; int bi = 0;
            for (int f = 0; f < NF_; ++f) {
                float v = bimp[f];
                if (v > best) { best = v; bi = f; }
            }
            bimp[bi] = -1e31f;
            selidx[base + kk] = bi;
            selact[base + kk] = (best > 0.f) ? 1 : 0;
        }
    }
    for (int it = tid; it < G_ * DH_; it += 256) {
        int g = it >> 7, d = it & 127;
        float a = 0.f;
        for (int j = 0; j < NWP_; ++j) a += sc[g][j] * cv[((size_t)kvh * NWP_ + j) * DH_ + d];
        coutb[(((size_t)(kvh * G_ + g)) * S_ + s) * DH_ + d] = a;
    }
}

// ---------------- selection attention (J = 80 keys) ----------------
__global__ __launch_bounds__(256) void selattn_kernel(
    const float* __restrict__ rq, const float* __restrict__ rk, const float* __restrict__ qkv,
    const int* __restrict__ selidx, const int* __restrict__ selact, float* __restrict__ foutb) {
    const int s = blockIdx.x, kvh = blockIdx.y, tid = threadIdx.x;
    const int J = (NSEL_ + 1) * SBS_;  // 80
    __shared__ float qs[G_][DH_];
    __shared__ float kl[80][DH_ + 1];
    __shared__ float sc[G_][80];
    __shared__ int posb[80];
    __shared__ int maskb[80];
    if (tid < J) {
        int b = tid >> 4, t = tid & 15;
        int p, ok;
        if (b < NSEL_) {
            int base = (kvh * S_ + s) * NSEL_ + b;
            int f = selidx[base];
            p = f * SBS_ + t;
            ok = selact[base] && (p <= s);
        } else {
            p = (s >> 4) * SBS_ + t;
            ok = (p <= s);
        }
        posb[tid] = p; maskb[tid] = ok;
    }
    for (int idx = tid; idx < G_ * DH_; idx += 256) {
        int g = idx >> 7, d = idx & 127;
        qs[g][d] = rq[(((size_t)(kvh * G_ + g)) * S_ + s) * DH_ + d];
    }
    __syncthreads();
    for (int idx = tid; idx < J * DH_; idx += 256) {
        int r = idx >> 7, d = idx & 127;
        kl[r][d] = rk[((size_t)kvh * S_ + posb[r]) * DH_ + d];
    }
    __syncthreads();
    for (int it = tid; it < G_ * J; it += 256) {
        int g = it / J, j = it % J;
        float a = 0.f;
#pragma unroll 8
        for (int d = 0; d < DH_; ++d) a += qs[g][d] * kl[j][d];
        sc[g][j] = maskb[j] ? a * SCALE_F : -INFINITY;
    }
    __syncthreads();
    const int wv = tid >> 6, ln = tid & 63;
    float v0 = sc[wv][ln];
    float v1 = (ln < J - 64) ? sc[wv][64 + ln] : -INFINITY;
    float m = fmaxf(v0, v1);
#pragma unroll
    for (int off = 32; off > 0; off >>= 1) m = fmaxf(m, __shfl_xor(m, off));
    float e0 = expf(v0 - m);
    float e1 = (ln < J - 64) ? expf(v1 - m) : 0.f;
    float ssum = e0 + e1;
#pragma unroll
    for (int off = 32; off > 0; off >>= 1) ssum += __shfl_xor(ssum, off);
    float inv = 1.f / ssum;
    sc[wv][ln] = e0 * inv;
    if (ln < J - 64) sc[wv][64 + ln] = e1 * inv;
    __syncthreads();
    for (int it = tid; it < G_ * DH_; it += 256) {
        int g = it >> 7, d = it & 127;
        float a = 0.f;
        for (int j = 0; j < J; ++j)
            a += sc[g][j] * qkv[(size_t)posb[j] * QKVN_ + (DIM_ + KVH_ * DH_) + kvh * DH_ + d];
        foutb[(((size_t)(kvh * G_ + g)) * S_ + s) * DH_ + d] = a;
    }
}

// ---------------- sliding window attention (J = 65 keys) ----------------
__global__ __launch_bounds__(256) void swattn_kernel(
    const float* __restrict__ rq, const float* __restrict__ rk, const float* __restrict__ qkv,
    float* __restrict__ swoutb) {
    const int s = blockIdx.x, kvh = blockIdx.y, tid = threadIdx.x;
    const int J = SW_ + 1;  // 65
    __shared__ float qs[G_][DH_];
    __shared__ float kl[65][DH_ + 1];
    __shared__ float sc[G_][65];
    for (int idx = tid; idx < G_ * DH_; idx += 256) {
        int g = idx >> 7, d = idx & 127;
        qs[g][d] = rq[(((size_t)(kvh * G_ + g)) * S_ + s) * DH_ + d];
    }
    for (int idx = tid; idx < J * DH_; idx += 256) {
        int r = idx >> 7, d = idx & 127;
        int p = s - SW_ + r;
        kl[r][d] = (p >= 0) ? rk[((size_t)kvh * S_ + p) * DH_ + d] : 0.f;
    }
    __syncthreads();
    for (int it = tid; it < G_ * J; it += 256) {
        int g = it / J, j = it % J;
        int p = s - SW_ + j;
        float a = 0.f;
#pragma unroll 8
        for (int d = 0; d < DH_; ++d) a += qs[g][d] * kl[j][d];
        sc[g][j] = (p >= 0) ? a * SCALE_F : -INFINITY;
    }
    __syncthreads();
    const int wv = tid >> 6, ln = tid & 63;
    float v0 = sc[wv][ln];
    float v1 = (ln < J - 64) ? sc[wv][64 + ln] : -INFINITY;
    float m = fmaxf(v0, v1);
#pragma unroll
    for (int off = 32; off > 0; off >>= 1) m = fmaxf(m, __shfl_xor(m, off));
    float e0 = expf(v0 - m);
    float e1 = (ln < J - 64) ? expf(v1 - m) : 0.f;
    float ssum = e0 + e1;
#pragma unroll
    for (int off = 32; off > 0; off >>= 1) ssum += __shfl_xor(ssum, off);
    float inv = 1.f / ssum;
    sc[wv][ln] = e0 * inv;
    if (ln < J - 64) sc[wv][64 + ln] = e1 * inv;
    __syncthreads();
    for (int it = tid; it < G_ * DH_; it += 256) {
        int g = it >> 7, d = it & 127;
        float a = 0.f;
        for (int j = 0; j < J; ++j) {
            int p = s - SW_ + j;
            int pc = p < 0 ? 0 : p;
            a += sc[g][j] * qkv[(size_t)pc * QKVN_ + (DIM_ + KVH_ * DH_) + kvh * DH_ + d];
        }
        swoutb[(((size_t)(kvh * G_ + g)) * S_ + s) * DH_ + d] = a;
    }
}

// ---------------- gating head ----------------
__global__ __launch_bounds__(256) void comb_kernel(const float* __restrict__ h,
    const float* __restrict__ w_comb, const float* __restrict__ b_comb, float* __restrict__ comb) {
    int s = blockIdx.x, tid = threadIdx.x;
    __shared__ float hrow[DIM_];
    for (int idx = tid; idx < DIM_; idx += 256) hrow[idx] = h[(size_t)s * DIM_ + idx];
    __syncthreads();
    if (tid < 192) {
        int o = tid >> 2, p = tid & 3;
        float a = 0.f;
        for (int d = p; d < DIM_; d += 4) a += hrow[d] * w_comb[(size_t)d * 48 + o];
        a += __shfl_xor(a, 1);
        a += __shfl_xor(a, 2);
        if (p == 0) comb[(size_t)s * 48 + o] = 1.f / (1.f + expf(-(a + b_comb[o])));
    }
}

// ---------------- combine branches with gates -> bf16 hi/lo ----------------
__global__ __launch_bounds__(256) void combine_kernel(const float* __restrict__ c0b,
    const float* __restrict__ c1b, const float* __restrict__ c2b,
    const float* __restrict__ comb, u16* __restrict__ comb_h, u16* __restrict__ comb_l) {
    size_t i = (size_t)blockIdx.x * 256 + threadIdx.x;
    int s = (int)(i >> 11);
    int hd = (int)(i & 2047);
    int hh = hd >> 7;
    int d = hd & 127;
    size_t src = ((size_t)hh * S_ + s) * DH_ + d;
    const float* cb = comb + (size_t)s * 48 + hh * 3;
    float v = c0b[src] * cb[0] + c1b[src] * cb[1] + c2b[src] * cb[2];
    u16 hb = f2bf(v);
    comb_h[i] = hb;
    comb_l[i] = f2bf(v - bf2f(hb));
}

extern "C" void kernel_launch(void* const* d_in, const int* in_sizes, int n_in,
                              void* d_out, int out_size, void* d_ws, size_t ws_size,
                              hipStream_t stream) {
    const float* x      = (const float*)d_in[0];
    const float* g_norm = (const float*)d_in[1];
    const float* w_qkv  = (const float*)d_in[2];
    const float* k_pos  = (const float*)d_in[3];
    const float* v_pos  = (const float*)d_in[4];
    const float* mem_kv = (const float*)d_in[5];
    const float* kc_w1  = (const float*)d_in[6];
    const float* kc_b1  = (const float*)d_in[7];
    const float* kc_w2  = (const float*)d_in[8];
    const float* kc_b2  = (const float*)d_in[9];
    const float* vc_w1  = (const float*)d_in[10];
    const float* vc_b1  = (const float*)d_in[11];
    const float* vc_w2  = (const float*)d_in[12];
    const float* vc_b2  = (const float*)d_in[13];
    const float* w_comb = (const float*)d_in[14];
    const float* b_comb = (const float*)d_in[15];
    const float* w_out  = (const float*)d_in[16];
    float* out = (float*)d_out;
    float* ws = (float*)d_ws;

    // Persistent: h(4194304) qkv(6291456) ckf(131072) cvf(131072)
    float* h   = ws;
    float* qkv = h + 4194304;
    float* ckf = qkv + 6291456;
    float* cvf = ckf + 131072;
    float* uni = cvf + 131072;   // union region, 3 sequential layouts

    // Layout X (steps 1-2): h splits + transposed/split w_qkv
    u16* h_hi    = (u16*)uni;            // 4,194,304 u16
    u16* h_lo    = h_hi + 4194304;
    u16* wqkvt_h = h_lo + 4194304;       // 6,291,456 u16
    u16* wqkvt_l = wqkvt_h + 6291456;    // X = 10,485,760 fl

    // Layout A (steps 3-6): w1 transposes + cin splits + chid + part
    u16* w1kt_h = (u16*)uni;             // 4,194,304 u16 each
    u16* w1kt_l = w1kt_h + 4194304;
    u16* w1vt_h = w1kt_l + 4194304;
    u16* w1vt_l = w1vt_h + 4194304;
    u16* cink_h = w1vt_l + 4194304;      // 2,088,960 u16 each
    u16* cink_l = cink_h + 2088960;
    u16* cinv_h = cink_l + 2088960;
    u16* cinv_l = cinv_h + 2088960;
    float* chid_k = uni + 12566528;      // 2,088,960 fl each
    float* chid_v = chid_k + 2088960;
    float* part   = chid_v + 2088960;    // 1,044,480 fl; A = 17,788,928 fl

    // Layout B (steps 7+): attention buffers
    float* rq     = uni;                 // 4,194,304
    float* rk     = rq + 4194304;        // 1,048,576
    float* coutb  = rk + 1048576;        // 4,194,304 (aliased by woutt after combine)
    float* foutb  = coutb + 4194304;     // 4,194,304
    float* swoutb = foutb + 4194304;     // 4,194,304
    float* combb  = swoutb + 4194304;    // 98,304
    u16* comb_h   = (u16*)(combb + 98304);   // 4,194,304 u16 (= 2,097,152 fl)
    u16* comb_l   = comb_h + 4194304;        // 4,194,304 u16 (= 2,097,152 fl)
    int* selidx   = (int*)(comb_l + 4194304);   // 32,768 ints
    int* selact   = selidx + 32768;             // 32,768 ints
    u16* woutt_h  = (u16*)coutb;         // 4,194,304 u16 each (fits in dead coutb)
    u16* woutt_l  = woutt_h + 4194304;

    // 1) RMSNorm + h split
    rmsnorm_kernel<<<S_, 256, 0, stream>>>(x, g_norm, h, h_hi, h_lo);
    // 2) split/transpose w_qkv, then qkv projection via bf16x3 MFMA
    tsplit_kernel<<<dim3(QKVN_ / 32, DIM_ / 32), 256, 0, stream>>>(w_qkv, wqkvt_h, wqkvt_l, DIM_, QKVN_);
    gemm_mfma_kernel<<<dim3(QKVN_ / 128, S_ / 128, 1), 256, 0, stream>>>(
        h_hi, h_lo, wqkvt_h, wqkvt_l, qkv, nullptr,
        h_hi, h_lo, wqkvt_h, wqkvt_l, qkv, nullptr, S_, QKVN_, DIM_, 0);
    // 3) w1 transposes (Layout A; X is dead now)
    tsplit_kernel<<<dim3(HID_ / 32, HID_ / 32), 256, 0, stream>>>(kc_w1, w1kt_h, w1kt_l, HID_, HID_);
    tsplit_kernel<<<dim3(HID_ / 32, HID_ / 32), 256, 0, stream>>>(vc_w1, w1vt_h, w1vt_l, HID_, HID_);
    // 4) compression MLP inputs (bf16 hi/lo)
    build_cin_kernel<<<dim3(NW_, KVH_, 2), 256, 0, stream>>>(qkv, k_pos, v_pos,
        cink_h, cink_l, cinv_h, cinv_l);
    // 5) w1 (relu+bias), dual bf16x3 MFMA -> chid fp32
    gemm_mfma_kernel<<<dim3(HID_ / 128, 8, 2), 256, 0, stream>>>(
        cink_h, cink_l, w1kt_h, w1kt_l, chid_k, kc_b1,
        cinv_h, cinv_l, w1vt_h, w1vt_l, chid_v, vc_b1, MROWS_, HID_, HID_, 1);
    // 6) w2 fp32 split-K + reduce/prepend
    gemm_w2sk_kernel<<<dim3(DH_ / 64, 16, 8), 256, 0, stream>>>(chid_k, chid_v, kc_w2, vc_w2, part);
    reduce_scatter_kernel<<<dim3(NWP_, KVH_, 2), 128, 0, stream>>>(part, mem_kv, kc_b2, vc_b2, ckf, cvf);
    // 7) RoPE (Layout B; A is dead now)
    rope_kernel<<<dim3(S_, HEADS_ + KVH_), 64, 0, stream>>>(qkv, rq, rk);
    // 8) attention branches
    compattn_kernel<<<dim3(S_, KVH_), 256, 0, stream>>>(qkv, ckf, cvf, coutb, selidx, selact);
    selattn_kernel<<<dim3(S_, KVH_), 256, 0, stream>>>(rq, rk, qkv, selidx, selact, foutb);
    swattn_kernel<<<dim3(S_, KVH_), 256, 0, stream>>>(rq, rk, qkv, swoutb);
    // 9) gating + combine (writes bf16 hi/lo of combined)
    comb_kernel<<<S_, 256, 0, stream>>>(h, w_comb, b_comb, combb);
    combine_kernel<<<(S_ * DIM_) / 256, 256, 0, stream>>>(coutb, foutb, swoutb, combb, comb_h, comb_l);
    // 10) split/transpose w_out (aliases dead coutb), then output projection
    tsplit_kernel<<<dim3(DIM_ / 32, DIM_ / 32), 256, 0, stream>>>(w_out, woutt_h, woutt_l, HEADS_ * DH_, DIM_);
    gemm_mfma_kernel<<<dim3(DIM_ / 128, S_ / 128, 1), 256, 0, stream>>>(
        comb_h, comb_l, woutt_h, woutt_l, out, nullptr,
        comb_h, comb_l, woutt_h, woutt_l, out, nullptr, S_, DIM_, HEADS_ * DH_, 0);
}

// Round 7
// 1202.091 us; speedup vs baseline: 1.6487x; 1.1498x over previous
//
#include <hip/hip_runtime.h>
#include <math.h>

#define S_ 2048
#define DIM_ 2048
#define HEADS_ 16
#define KVH_ 4
#define G_ 4
#define DH_ 128
#define NW_ 255
#define NWP_ 256
#define CBS_ 16
#define CST_ 8
#define SBS_ 16
#define NSEL_ 4
#define NF_ 128
#define SW_ 64
#define QKVN_ 3072
#define HID_ 2048
#define MROWS_ 1020   // KVH_*NW_
#define SCALE_F 0.08838834764831845f

typedef unsigned short u16;
typedef u16 u16x8 __attribute__((ext_vector_type(8)));
typedef short bf16x8 __attribute__((ext_vector_type(8)));
typedef float f32x4 __attribute__((ext_vector_type(4)));

__device__ __forceinline__ u16 f2bf(float x) {
    unsigned int u = __float_as_uint(x);
    u += 0x7fffu + ((u >> 16) & 1u);
    return (u16)(u >> 16);
}
__device__ __forceinline__ float bf2f(u16 b) {
    return __uint_as_float(((unsigned int)b) << 16);
}

// ---------------- RMSNorm (+ bf16 hi/lo split of h) ----------------
__global__ __launch_bounds__(256) void rmsnorm_kernel(const float* __restrict__ x,
    const float* __restrict__ g, float* __restrict__ h,
    u16* __restrict__ h_hi, u16* __restrict__ h_lo) {
    int s = blockIdx.x, tid = threadIdx.x;
    const float* row = x + (size_t)s * DIM_;
    float ss = 0.f;
    for (int idx = tid; idx < DIM_ / 4; idx += 256) {
        float4 v = reinterpret_cast<const float4*>(row)[idx];
        ss += v.x * v.x + v.y * v.y + v.z * v.z + v.w * v.w;
    }
    __shared__ float red[256];
    red[tid] = ss; __syncthreads();
    for (int o = 128; o > 0; o >>= 1) { if (tid < o) red[tid] += red[tid + o]; __syncthreads(); }
    float scale = 1.0f / sqrtf(red[0] / (float)DIM_ + 1e-6f);
    for (int idx = tid; idx < DIM_; idx += 256) {
        float v = row[idx] * scale * g[idx];
        size_t o = (size_t)s * DIM_ + idx;
        h[o] = v;
        u16 hb = f2bf(v);
        h_hi[o] = hb;
        h_lo[o] = f2bf(v - bf2f(hb));
    }
}

// ---------------- transpose + bf16 hi/lo split: W[K][N] -> Th/Tl[N][K] ----------------
__global__ __launch_bounds__(256) void tsplit_kernel(const float* __restrict__ W,
    u16* __restrict__ Th, u16* __restrict__ Tl, int K, int N) {
    __shared__ float t[32][33];
    int n0 = blockIdx.x * 32, k0 = blockIdx.y * 32;
    int tx = threadIdx.x & 31, ty = threadIdx.x >> 5;  // 32 x 8
#pragma unroll
    for (int j = 0; j < 4; ++j)
        t[ty + j * 8][tx] = W[(size_t)(k0 + ty + j * 8) * N + n0 + tx];
    __syncthreads();
#pragma unroll
    for (int j = 0; j < 4; ++j) {
        float v = t[tx][ty + j * 8];   // k = k0+tx, n = n0+ty+j*8
        u16 hb = f2bf(v);
        size_t o = (size_t)(n0 + ty + j * 8) * K + k0 + tx;
        Th[o] = hb;
        Tl[o] = f2bf(v - bf2f(hb));
    }
}

// ---------------- bf16x3 MFMA GEMM: C = act(Ah+Al)@(Bh+Bl)^T_layout + bias ----------------
__global__ __launch_bounds__(256, 2) void gemm_mfma_kernel(
    const u16* __restrict__ Ah0, const u16* __restrict__ Al0,
    const u16* __restrict__ Bh0, const u16* __restrict__ Bl0,
    float* __restrict__ C0, const float* __restrict__ bias0,
    const u16* __restrict__ Ah1, const u16* __restrict__ Al1,
    const u16* __restrict__ Bh1, const u16* __restrict__ Bl1,
    float* __restrict__ C1, const float* __restrict__ bias1,
    int M, int N, int K, int act) {
    const int pair = blockIdx.z;
    const u16* Ah = pair ? Ah1 : Ah0;
    const u16* Al = pair ? Al1 : Al0;
    const u16* Bh = pair ? Bh1 : Bh0;
    const u16* Bl = pair ? Bl1 : Bl0;
    float* C = pair ? C1 : C0;
    const float* bias = pair ? bias1 : bias0;

    __shared__ u16 sAh[128][56], sAl[128][56], sBh[128][56], sBl[128][56];
    const int tid = threadIdx.x;
    const int bm = blockIdx.y * 128, bn = blockIdx.x * 128;
    const int s0r = tid >> 2, sc = (tid & 3) * 8;
    const int s1r = s0r + 64;
    const int lane = tid & 63;
    const int wv = tid >> 6;
    const int wm = (wv >> 1) * 64, wn = (wv & 1) * 64;
    const int fr = lane & 15;
    const int fk = (lane >> 4) * 8;

    f32x4 acc[4][4];
#pragma unroll
    for (int i = 0; i < 4; ++i)
#pragma unroll
        for (int j = 0; j < 4; ++j) acc[i][j] = (f32x4){0.f, 0.f, 0.f, 0.f};

    const u16x8 zz = {0, 0, 0, 0, 0, 0, 0, 0};
    for (int k0 = 0; k0 < K; k0 += 32) {
        const bool g0 = (bm + s0r) < M, g1 = (bm + s1r) < M;
        const size_t a0 = (size_t)(bm + s0r) * K + k0 + sc;
        const size_t a1 = (size_t)(bm + s1r) * K + k0 + sc;
        const size_t b0 = (size_t)(bn + s0r) * K + k0 + sc;
        const size_t b1 = (size_t)(bn + s1r) * K + k0 + sc;
        u16x8 a0h = g0 ? *(const u16x8*)(Ah + a0) : zz;
        u16x8 a0l = g0 ? *(const u16x8*)(Al + a0) : zz;
        u16x8 a1h = g1 ? *(const u16x8*)(Ah + a1) : zz;
        u16x8 a1l = g1 ? *(const u16x8*)(Al + a1) : zz;
        u16x8 b0h = *(const u16x8*)(Bh + b0);
        u16x8 b0l = *(const u16x8*)(Bl + b0);
        u16x8 b1h = *(const u16x8*)(Bh + b1);
        u16x8 b1l = *(const u16x8*)(Bl + b1);
        __syncthreads();
        *(u16x8*)&sAh[s0r][sc] = a0h; *(u16x8*)&sAl[s0r][sc] = a0l;
        *(u16x8*)&sAh[s1r][sc] = a1h; *(u16x8*)&sAl[s1r][sc] = a1l;
        *(u16x8*)&sBh[s0r][sc] = b0h; *(u16x8*)&sBl[s0r][sc] = b0l;
        *(u16x8*)&sBh[s1r][sc] = b1h; *(u16x8*)&sBl[s1r][sc] = b1l;
        __syncthreads();
        bf16x8 ah[4], al[4], bh[4], bl[4];
#pragma unroll
        for (int i = 0; i < 4; ++i) {
            ah[i] = *(const bf16x8*)&sAh[wm + i * 16 + fr][fk];
            al[i] = *(const bf16x8*)&sAl[wm + i * 16 + fr][fk];
            bh[i] = *(const bf16x8*)&sBh[wn + i * 16 + fr][fk];
            bl[i] = *(const bf16x8*)&sBl[wn + i * 16 + fr][fk];
        }
#pragma unroll
        for (int i = 0; i < 4; ++i)
#pragma unroll
            for (int j = 0; j < 4; ++j) {
                acc[i][j] = __builtin_amdgcn_mfma_f32_16x16x32_bf16(ah[i], bh[j], acc[i][j], 0, 0, 0);
                acc[i][j] = __builtin_amdgcn_mfma_f32_16x16x32_bf16(ah[i], bl[j], acc[i][j], 0, 0, 0);
                acc[i][j] = __builtin_amdgcn_mfma_f32_16x16x32_bf16(al[i], bh[j], acc[i][j], 0, 0, 0);
            }
    }
    const int rq4 = (lane >> 4) * 4;
#pragma unroll
    for (int i = 0; i < 4; ++i) {
        const int rbase = bm + wm + i * 16 + rq4;
#pragma unroll
        for (int j = 0; j < 4; ++j) {
            const int col = bn + wn + j * 16 + fr;
            const float bv = bias ? bias[col] : 0.f;
#pragma unroll
            for (int r = 0; r < 4; ++r) {
                const int row = rbase + r;
                if (row < M) {
                    float v = acc[i][j][r] + bv;
                    if (act == 1) v = fmaxf(v, 0.f);
                    C[(size_t)row * N + col] = v;
                }
            }
        }
    }
}

// ---------------- dual split-K w2 GEMM (fp32): 1020x128x2048, 64x64 tile ----------------
__global__ __launch_bounds__(256) void gemm_w2sk_kernel(
    const float* __restrict__ Ak, const float* __restrict__ Av,
    const float* __restrict__ Bk, const float* __restrict__ Bv,
    float* __restrict__ part) {
    const int pair = blockIdx.z >> 2, ks = blockIdx.z & 3;
    const float* A = pair ? Av : Ak;   // 1020 x 2048
    const float* B = pair ? Bv : Bk;   // 2048 x 128
    __shared__ float As[16][64];
    __shared__ float Bs[16][64];
    const int tid = threadIdx.x;
    const int bm = blockIdx.y * 64, bn = blockIdx.x * 64;
    const int tx = tid & 15, ty = tid >> 4;
    const int ar = tid >> 2, ac = (tid & 3) << 2;
    const int br = tid >> 4, bc = (tid & 15) << 2;
    const int k_lo = ks * 512;
    float acc[4][4] = {};
    for (int k0 = k_lo; k0 < k_lo + 512; k0 += 16) {
        float4 av = make_float4(0.f, 0.f, 0.f, 0.f);
        if (bm + ar < MROWS_) av = *reinterpret_cast<const float4*>(A + (size_t)(bm + ar) * HID_ + k0 + ac);
        float4 bv = *reinterpret_cast<const float4*>(B + (size_t)(k0 + br) * DH_ + bn + bc);
        __syncthreads();
        As[ac + 0][ar] = av.x; As[ac + 1][ar] = av.y; As[ac + 2][ar] = av.z; As[ac + 3][ar] = av.w;
        *reinterpret_cast<float4*>(&Bs[br][bc]) = bv;
        __syncthreads();
#pragma unroll
        for (int k = 0; k < 16; ++k) {
            float4 a = *reinterpret_cast<const float4*>(&As[k][ty << 2]);
            float4 b = *reinterpret_cast<const float4*>(&Bs[k][tx << 2]);
            float aa[4] = {a.x, a.y, a.z, a.w};
            float bb[4] = {b.x, b.y, b.z, b.w};
#pragma unroll
            for (int i = 0; i < 4; ++i)
#pragma unroll
                for (int j = 0; j < 4; ++j) acc[i][j] += aa[i] * bb[j];
        }
        __syncthreads();
    }
    const int row0 = bm + (ty << 2), col0 = bn + (tx << 2);
    float* dst = part + ((size_t)(pair * 4 + ks) * MROWS_) * DH_;
#pragma unroll
    for (int i = 0; i < 4; ++i) {
        int r = row0 + i;
        if (r < MROWS_)
            *reinterpret_cast<float4*>(dst + (size_t)r * DH_ + col0) =
                make_float4(acc[i][0], acc[i][1], acc[i][2], acc[i][3]);
    }
}

// ---------- reduce split-K partials + bias, prepend mem row; emit bf16 hi/lo ----------
// pair=0: ck -> ckh/ckl [kvh][256][128] (key-major). pair=1: cv -> cvth/cvtl [kvh][128][256] (d-major).
__global__ __launch_bounds__(128) void reduce_scatter_kernel(
    const float* __restrict__ part, const float* __restrict__ mem,
    const float* __restrict__ bk, const float* __restrict__ bv,
    u16* __restrict__ ckh, u16* __restrict__ ckl,
    u16* __restrict__ cvth, u16* __restrict__ cvtl) {
    const int r = blockIdx.x, kvh = blockIdx.y, pair = blockIdx.z, d = threadIdx.x;
    float v;
    if (r == 0) {
        v = mem[(size_t)pair * KVH_ * DH_ + kvh * DH_ + d];
    } else {
        const size_t row = (size_t)kvh * NW_ + (r - 1);
        const float* p0 = part + ((size_t)pair * 4 * MROWS_ + row) * DH_ + d;
        const size_t stride = (size_t)MROWS_ * DH_;
        v = p0[0] + p0[stride] + p0[2 * stride] + p0[3 * stride];
        v += (pair ? bv[d] : bk[d]);
    }
    u16 hb = f2bf(v);
    u16 lb = f2bf(v - bf2f(hb));
    if (pair == 0) {
        size_t o = ((size_t)kvh * NWP_ + r) * DH_ + d;
        ckh[o] = hb; ckl[o] = lb;
    } else {
        size_t o = ((size_t)kvh * DH_ + d) * NWP_ + r;
        cvth[o] = hb; cvtl[o] = lb;
    }
}

// ---------------- build compression-MLP inputs (bf16 hi/lo), k and v ----------------
__global__ __launch_bounds__(256) void build_cin_kernel(const float* __restrict__ qkv,
    const float* __restrict__ k_pos, const float* __restrict__ v_pos,
    u16* __restrict__ cink_h, u16* __restrict__ cink_l,
    u16* __restrict__ cinv_h, u16* __restrict__ cinv_l) {
    int w = blockIdx.x, kvh = blockIdx.y, pair = blockIdx.z, tid = threadIdx.x;
    const float* posw = pair ? v_pos : k_pos;
    u16* ch = pair ? cinv_h : cink_h;
    u16* cl = pair ? cinv_l : cink_l;
    const int col_off = pair ? (DIM_ + KVH_ * DH_) : DIM_;
    for (int idx = tid; idx < CBS_ * DH_; idx += 256) {
        int t = idx >> 7, d = idx & 127;
        int srow = w * CST_ + t;
        float v = qkv[(size_t)srow * QKVN_ + col_off + kvh * DH_ + d] + posw[(kvh * CBS_ + t) * DH_ + d];
        size_t o = ((size_t)kvh * NW_ + w) * HID_ + idx;
        u16 hb = f2bf(v);
        ch[o] = hb;
        cl[o] = f2bf(v - bf2f(hb));
    }
}

// ---------------- RoPE for q (16 heads) and k (4 heads) ----------------
__global__ __launch_bounds__(64) void rope_kernel(const float* __restrict__ qkv,
    float* __restrict__ rq, float* __restrict__ rk) {
    int s = blockIdx.x, head = blockIdx.y, i = threadIdx.x;
    float inv = 1.0f / powf(10000.0f, (float)i / 64.0f);
    float ang = (float)s * inv;
    float c = cosf(ang), sn = sinf(ang);
    const float* src; float* dst;
    if (head < HEADS_) {
        src = qkv + (size_t)s * QKVN_ + head * DH_;
        dst = rq + ((size_t)head * S_ + s) * DH_;
    } else {
        int kvh = head - HEADS_;
        src = qkv + (size_t)s * QKVN_ + DIM_ + kvh * DH_;
        dst = rk + ((size_t)kvh * S_ + s) * DH_;
    }
    float t1 = src[2 * i], t2 = src[2 * i + 1];
    dst[2 * i] = t1 * c - t2 * sn;
    dst[2 * i + 1] = t1 * sn + t2 * c;
}

// ------- compression attention via MFMA: 16 queries x 4 g per block + top-k -------
__global__ __launch_bounds__(256) void compattn_mfma_kernel(
    const float* __restrict__ qkv,
    const u16* __restrict__ ckh, const u16* __restrict__ ckl,
    const u16* __restrict__ cvth, const u16* __restrict__ cvtl,
    float* __restrict__ coutb, int* __restrict__ selidx, int* __restrict__ selact) {
    const int s0 = blockIdx.x * 16, kvh = blockIdx.y;
    const int tid = threadIdx.x, lane = tid & 63, w = tid >> 6;
    const int fr = lane & 15, fq = lane >> 4;
    __shared__ u16 attn_h[4][16][264];
    __shared__ u16 attn_l[4][16][264];
    __shared__ float bimpS[16][128];

    // Q fragments: rows = 16 queries, head = kvh*G + w
    bf16x8 qh[4], ql[4];
    {
        const float* qbase = qkv + (size_t)(s0 + fr) * QKVN_ + (kvh * G_ + w) * DH_;
#pragma unroll
        for (int kk = 0; kk < 4; ++kk) {
            int d0 = kk * 32 + fq * 8;
            float4 v0 = *reinterpret_cast<const float4*>(qbase + d0);
            float4 v1 = *reinterpret_cast<const float4*>(qbase + d0 + 4);
            float vv[8] = {v0.x, v0.y, v0.z, v0.w, v1.x, v1.y, v1.z, v1.w};
            u16x8 hh, ll;
#pragma unroll
            for (int j = 0; j < 8; ++j) {
                u16 hb = f2bf(vv[j]);
                hh[j] = hb; ll[j] = f2bf(vv[j] - bf2f(hb));
            }
            qh[kk] = *(bf16x8*)&hh; ql[kk] = *(bf16x8*)&ll;
        }
    }
    // QK^T: 16 column tiles of 16 keys each (256 keys total)
    f32x4 sc[16];
#pragma unroll
    for (int ct = 0; ct < 16; ++ct) {
        f32x4 acc = (f32x4){0.f, 0.f, 0.f, 0.f};
        const u16* kbh = ckh + ((size_t)kvh * NWP_ + ct * 16 + fr) * DH_ + fq * 8;
        const u16* kbl = ckl + ((size_t)kvh * NWP_ + ct * 16 + fr) * DH_ + fq * 8;
#pragma unroll
        for (int kk = 0; kk < 4; ++kk) {
            bf16x8 bh = *(const bf16x8*)(kbh + kk * 32);
            bf16x8 bl = *(const bf16x8*)(kbl + kk * 32);
            acc = __builtin_amdgcn_mfma_f32_16x16x32_bf16(qh[kk], bh, acc, 0, 0, 0);
            acc = __builtin_amdgcn_mfma_f32_16x16x32_bf16(ql[kk], bh, acc, 0, 0, 0);
            acc = __builtin_amdgcn_mfma_f32_16x16x32_bf16(qh[kk], bl, acc, 0, 0, 0);
        }
        sc[ct] = acc;
    }
    // mask + scale + in-register softmax (row = query fq*4+ri; col = ct*16+fr)
    float mrow[4], rsum[4], rinv[4];
#pragma unroll
    for (int ri = 0; ri < 4; ++ri) mrow[ri] = -INFINITY;
#pragma unroll
    for (int ct = 0; ct < 16; ++ct) {
        int j = ct * 16 + fr;
#pragma unroll
        for (int ri = 0; ri < 4; ++ri) {
            int s = s0 + fq * 4 + ri;
            bool vis = (j == 0) || (s > (j - 1) * CST_ + CBS_ - 1);
            float v = vis ? sc[ct][ri] * SCALE_F : -INFINITY;
            sc[ct][ri] = v;
            mrow[ri] = fmaxf(mrow[ri], v);
        }
    }
#pragma unroll
    for (int off = 8; off >= 1; off >>= 1)
#pragma unroll
        for (int ri = 0; ri < 4; ++ri) mrow[ri] = fmaxf(mrow[ri], __shfl_xor(mrow[ri], off));
#pragma unroll
    for (int ri = 0; ri < 4; ++ri) rsum[ri] = 0.f;
#pragma unroll
    for (int ct = 0; ct < 16; ++ct)
#pragma unroll
        for (int ri = 0; ri < 4; ++ri) {
            float e = expf(sc[ct][ri] - mrow[ri]);
            sc[ct][ri] = e; rsum[ri] += e;
        }
#pragma unroll
    for (int off = 8; off >= 1; off >>= 1)
#pragma unroll
        for (int ri = 0; ri < 4; ++ri) rsum[ri] += __shfl_xor(rsum[ri], off);
#pragma unroll
    for (int ri = 0; ri < 4; ++ri) rinv[ri] = 1.f / rsum[ri];
    // attn -> LDS (bf16 hi/lo)
#pragma unroll
    for (int ct = 0; ct < 16; ++ct)
#pragma unroll
        for (int ri = 0; ri < 4; ++ri) {
            float a = sc[ct][ri] * rinv[ri];
            u16 hb = f2bf(a);
            attn_h[w][fq * 4 + ri][ct * 16 + fr] = hb;
            attn_l[w][fq * 4 + ri][ct * 16 + fr] = f2bf(a - bf2f(hb));
        }
    __syncthreads();
    // block importance: bimp[sq][f] = (1/8) * sum_g (attn[2f+1] + attn[2f+2])
    for (int idx = tid; idx < 16 * 128; idx += 256) {
        int sq = idx >> 7, f = idx & 127;
        int j1 = 2 * f + 1, j2 = 2 * f + 2;
        float a = 0.f;
#pragma unroll
        for (int g = 0; g < 4; ++g) {
            a += bf2f(attn_h[g][sq][j1]) + bf2f(attn_l[g][sq][j1]);
            if (f < 127) a += bf2f(attn_h[g][sq][j2]) + bf2f(attn_l[g][sq][j2]);
        }
        float v = a * 0.125f;
        bimpS[sq][f] = (f < (s0 >> 4)) ? v : -1.0f;
    }
    __syncthreads();
    // serial top-4 per query (strict >, lowest index wins)
    if (tid < 16) {
        int s = s0 + tid;
        int base = (kvh * S_ + s) * NSEL_;
        for (int kk = 0; kk < NSEL_; ++kk) {
            float best = -1e30f; int bi = 0;
            for (int f = 0; f < NF_; ++f) {
                float v = bimpS[tid][f];
                if (v > best) { best = v; bi = f; }
            }
            bimpS[tid][bi] = -1e31f;
            selidx[base + kk] = bi;
            selact[base + kk] = (best > 0.f) ? 1 : 0;
        }
    }
    // PV: out[16 x 128] = attn[16 x 256] @ cv[256 x 128] (cv stored d-major)
    f32x4 po[8];
#pragma unroll
    for (int dt = 0; dt < 8; ++dt) po[dt] = (f32x4){0.f, 0.f, 0.f, 0.f};
#pragma unroll
    for (int jc = 0; jc < 8; ++jc) {
        bf16x8 ah = *(const bf16x8*)&attn_h[w][fr][jc * 32 + fq * 8];
        bf16x8 al = *(const bf16x8*)&attn_l[w][fr][jc * 32 + fq * 8];
#pragma unroll
        for (int dt = 0; dt < 8; ++dt) {
            const u16* vbh = cvth + ((size_t)kvh * DH_ + dt * 16 + fr) * NWP_ + jc * 32 + fq * 8;
            const u16* vbl = cvtl + ((size_t)kvh * DH_ + dt * 16 + fr) * NWP_ + jc * 32 + fq * 8;
            bf16x8 bh = *(const bf16x8*)vbh;
            bf16x8 bl = *(const bf16x8*)vbl;
            po[dt] = __builtin_amdgcn_mfma_f32_16x16x32_bf16(ah, bh, po[dt], 0, 0, 0);
            po[dt] = __builtin_amdgcn_mfma_f32_16x16x32_bf16(al, bh, po[dt], 0, 0, 0);
            po[dt] = __builtin_amdgcn_mfma_f32_16x16x32_bf16(ah, bl, po[dt], 0, 0, 0);
        }
    }
#pragma unroll
    for (int dt = 0; dt < 8; ++dt)
#pragma unroll
        for (int ri = 0; ri < 4; ++ri) {
            int sq = fq * 4 + ri;
            coutb[(((size_t)(kvh * G_ + w)) * S_ + s0 + sq) * DH_ + dt * 16 + fr] = po[dt][ri];
        }
}

// ---------------- selection attention (J = 80 keys) ----------------
__global__ __launch_bounds__(256) void selattn_kernel(
    const float* __restrict__ rq, const float* __restrict__ rk, const float* __restrict__ qkv,
    const int* __restrict__ selidx, const int* __restrict__ selact, float* __restrict__ foutb) {
    const int s = blockIdx.x, kvh = blockIdx.y, tid = threadIdx.x;
    const int J = (NSEL_ + 1) * SBS_;  // 80
    __shared__ float qs[G_][DH_];
    __shared__ float kl[80][DH_ + 1];
    __shared__ float sc[G_][80];
    __shared__ int posb[80];
    __shared__ int maskb[80];
    if (tid < J) {
        int b = tid >> 4, t = tid & 15;
        int p, ok;
        if (b < NSEL_) {
            int base = (kvh * S_ + s) * NSEL_ + b;
            int f = selidx[base];
            p = f * SBS_ + t;
            ok = selact[base] && (p <= s);
        } else {
            p = (s >> 4) * SBS_ + t;
            ok = (p <= s);
        }
        posb[tid] = p; maskb[tid] = ok;
    }
    for (int idx = tid; idx < G_ * DH_; idx += 256) {
        int g = idx >> 7, d = idx & 127;
        qs[g][d] = rq[(((size_t)(kvh * G_ + g)) * S_ + s) * DH_ + d];
    }
    __syncthreads();
    for (int idx = tid; idx < J * DH_; idx += 256) {
        int r = idx >> 7, d = idx & 127;
        kl[r][d] = rk[((size_t)kvh * S_ + posb[r]) * DH_ + d];
    }
    __syncthreads();
    for (int it = tid; it < G_ * J; it += 256) {
        int g = it / J, j = it % J;
        float a = 0.f;
#pragma unroll 8
        for (int d = 0; d < DH_; ++d) a += qs[g][d] * kl[j][d];
        sc[g][j] = maskb[j] ? a * SCALE_F : -INFINITY;
    }
    __syncthreads();
    const int wv = tid >> 6, ln = tid & 63;
    float v0 = sc[wv][ln];
    float v1 = (ln < J - 64) ? sc[wv][64 + ln] : -INFINITY;
    float m = fmaxf(v0, v1);
#pragma unroll
    for (int off = 32; off > 0; off >>= 1) m = fmaxf(m, __shfl_xor(m, off));
    float e0 = expf(v0 - m);
    float e1 = (ln < J - 64) ? expf(v1 - m) : 0.f;
    float ssum = e0 + e1;
#pragma unroll
    for (int off = 32; off > 0; off >>= 1) ssum += __shfl_xor(ssum, off);
    float inv = 1.f / ssum;
    sc[wv][ln] = e0 * inv;
    if (ln < J - 64) sc[wv][64 + ln] = e1 * inv;
    __syncthreads();
    for (int it = tid; it < G_ * DH_; it += 256) {
        int g = it >> 7, d = it & 127;
        float a = 0.f;
        for (int j = 0; j < J; ++j)
            a += sc[g][j] * qkv[(size_t)posb[j] * QKVN_ + (DIM_ + KVH_ * DH_) + kvh * DH_ + d];
        foutb[(((size_t)(kvh * G_ + g)) * S_ + s) * DH_ + d] = a;
    }
}

// ---------------- sliding window attention (J = 65 keys) ----------------
__global__ __launch_bounds__(256) void swattn_kernel(
    const float* __restrict__ rq, const float* __restrict__ rk, const float* __restrict__ qkv,
    float* __restrict__ swoutb) {
    const int s = blockIdx.x, kvh = blockIdx.y, tid = threadIdx.x;
    const int J = SW_ + 1;  // 65
    __shared__ float qs[G_][DH_];
    __shared__ float kl[65][DH_ + 1];
    __shared__ float sc[G_][65];
    for (int idx = tid; idx < G_ * DH_; idx += 256) {
        int g = idx >> 7, d = idx & 127;
        qs[g][d] = rq[(((size_t)(kvh * G_ + g)) * S_ + s) * DH_ + d];
    }
    for (int idx = tid; idx < J * DH_; idx += 256) {
        int r = idx >> 7, d = idx & 127;
        int p = s - SW_ + r;
        kl[r][d] = (p >= 0) ? rk[((size_t)kvh * S_ + p) * DH_ + d] : 0.f;
    }
    __syncthreads();
    for (int it = tid; it < G_ * J; it += 256) {
        int g = it / J, j = it % J;
        int p = s - SW_ + j;
        float a = 0.f;
#pragma unroll 8
        for (int d = 0; d < DH_; ++d) a += qs[g][d] * kl[j][d];
        sc[g][j] = (p >= 0) ? a * SCALE_F : -INFINITY;
    }
    __syncthreads();
    const int wv = tid >> 6, ln = tid & 63;
    float v0 = sc[wv][ln];
    float v1 = (ln < J - 64) ? sc[wv][64 + ln] : -INFINITY;
    float m = fmaxf(v0, v1);
#pragma unroll
    for (int off = 32; off > 0; off >>= 1) m = fmaxf(m, __shfl_xor(m, off));
    float e0 = expf(v0 - m);
    float e1 = (ln < J - 64) ? expf(v1 - m) : 0.f;
    float ssum = e0 + e1;
#pragma unroll
    for (int off = 32; off > 0; off >>= 1) ssum += __shfl_xor(ssum, off);
    float inv = 1.f / ssum;
    sc[wv][ln] = e0 * inv;
    if (ln < J - 64) sc[wv][64 + ln] = e1 * inv;
    __syncthreads();
    for (int it = tid; it < G_ * DH_; it += 256) {
        int g = it >> 7, d = it & 127;
        float a = 0.f;
        for (int j = 0; j < J; ++j) {
            int p = s - SW_ + j;
            int pc = p < 0 ? 0 : p;
            a += sc[g][j] * qkv[(size_t)pc * QKVN_ + (DIM_ + KVH_ * DH_) + kvh * DH_ + d];
        }
        swoutb[(((size_t)(kvh * G_ + g)) * S_ + s) * DH_ + d] = a;
    }
}

// ---------------- gating head ----------------
__global__ __launch_bounds__(256) void comb_kernel(const float* __restrict__ h,
    const float* __restrict__ w_comb, const float* __restrict__ b_comb, float* __restrict__ comb) {
    int s = blockIdx.x, tid = threadIdx.x;
    __shared__ float hrow[DIM_];
    for (int idx = tid; idx < DIM_; idx += 256) hrow[idx] = h[(size_t)s * DIM_ + idx];
    __syncthreads();
    if (tid < 192) {
        int o = tid >> 2, p = tid & 3;
        float a = 0.f;
        for (int d = p; d < DIM_; d += 4) a += hrow[d] * w_comb[(size_t)d * 48 + o];
        a += __shfl_xor(a, 1);
        a += __shfl_xor(a, 2);
        if (p == 0) comb[(size_t)s * 48 + o] = 1.f / (1.f + expf(-(a + b_comb[o])));
    }
}

// ---------------- combine branches with gates -> bf16 hi/lo ----------------
__global__ __launch_bounds__(256) void combine_kernel(const float* __restrict__ c0b,
    const float* __restrict__ c1b, const float* __restrict__ c2b,
    const float* __restrict__ comb, u16* __restrict__ comb_h, u16* __restrict__ comb_l) {
    size_t i = (size_t)blockIdx.x * 256 + threadIdx.x;
    int s = (int)(i >> 11);
    int hd = (int)(i & 2047);
    int hh = hd >> 7;
    int d = hd & 127;
    size_t src = ((size_t)hh * S_ + s) * DH_ + d;
    const float* cb = comb + (size_t)s * 48 + hh * 3;
    float v = c0b[src] * cb[0] + c1b[src] * cb[1] + c2b[src] * cb[2];
    u16 hb = f2bf(v);
    comb_h[i] = hb;
    comb_l[i] = f2bf(v - bf2f(hb));
}

extern "C" void kernel_launch(void* const* d_in, const int* in_sizes, int n_in,
                              void* d_out, int out_size, void* d_ws, size_t ws_size,
                              hipStream_t stream) {
    const float* x      = (const float*)d_in[0];
    const float* g_norm = (const float*)d_in[1];
    const float* w_qkv  = (const float*)d_in[2];
    const float* k_pos  = (const float*)d_in[3];
    const float* v_pos  = (const float*)d_in[4];
    const float* mem_kv = (const float*)d_in[5];
    const float* kc_w1  = (const float*)d_in[6];
    const float* kc_b1  = (const float*)d_in[7];
    const float* kc_w2  = (const float*)d_in[8];
    const float* kc_b2  = (const float*)d_in[9];
    const float* vc_w1  = (const float*)d_in[10];
    const float* vc_b1  = (const float*)d_in[11];
    const float* vc_w2  = (const float*)d_in[12];
    const float* vc_b2  = (const float*)d_in[13];
    const float* w_comb = (const float*)d_in[14];
    const float* b_comb = (const float*)d_in[15];
    const float* w_out  = (const float*)d_in[16];
    float* out = (float*)d_out;
    float* ws = (float*)d_ws;

    // Persistent: h(4194304) qkv(6291456) + compressed-kv bf16 arrays (262144 fl worth)
    float* h   = ws;
    float* qkv = h + 4194304;
    u16* ckh  = (u16*)(qkv + 6291456);   // 131,072 u16 each
    u16* ckl  = ckh + 131072;
    u16* cvth = ckl + 131072;
    u16* cvtl = cvth + 131072;
    float* uni = qkv + 6291456 + 262144; // union region, 3 sequential layouts

    // Layout X (steps 1-2): h splits + transposed/split w_qkv
    u16* h_hi    = (u16*)uni;            // 4,194,304 u16
    u16* h_lo    = h_hi + 4194304;
    u16* wqkvt_h = h_lo + 4194304;       // 6,291,456 u16
    u16* wqkvt_l = wqkvt_h + 6291456;

    // Layout A (steps 3-6): w1 transposes + cin splits + chid + part
    u16* w1kt_h = (u16*)uni;             // 4,194,304 u16 each
    u16* w1kt_l = w1kt_h + 4194304;
    u16* w1vt_h = w1kt_l + 4194304;
    u16* w1vt_l = w1vt_h + 4194304;
    u16* cink_h = w1vt_l + 4194304;      // 2,088,960 u16 each
    u16* cink_l = cink_h + 2088960;
    u16* cinv_h = cink_l + 2088960;
    u16* cinv_l = cinv_h + 2088960;
    float* chid_k = uni + 12566528;      // 2,088,960 fl each
    float* chid_v = chid_k + 2088960;
    float* part   = chid_v + 2088960;    // 1,044,480 fl

    // Layout B (steps 7+): attention buffers
    float* rq     = uni;                 // 4,194,304
    float* rk     = rq + 4194304;        // 1,048,576
    float* coutb  = rk + 1048576;        // 4,194,304 (aliased by woutt after combine)
    float* foutb  = coutb + 4194304;     // 4,194,304
    float* swoutb = foutb + 4194304;     // 4,194,304
    float* combb  = swoutb + 4194304;    // 98,304
    u16* comb_h   = (u16*)(combb + 98304);      // 4,194,304 u16
    u16* comb_l   = comb_h + 4194304;           // 4,194,304 u16
    int* selidx   = (int*)(comb_l + 4194304);   // 32,768 ints
    int* selact   = selidx + 32768;             // 32,768 ints
    u16* woutt_h  = (u16*)coutb;         // 4,194,304 u16 each (fits in dead coutb)
    u16* woutt_l  = woutt_h + 4194304;

    // 1) RMSNorm + h split
    rmsnorm_kernel<<<S_, 256, 0, stream>>>(x, g_norm, h, h_hi, h_lo);
    // 2) split/transpose w_qkv, then qkv projection via bf16x3 MFMA
    tsplit_kernel<<<dim3(QKVN_ / 32, DIM_ / 32), 256, 0, stream>>>(w_qkv, wqkvt_h, wqkvt_l, DIM_, QKVN_);
    gemm_mfma_kernel<<<dim3(QKVN_ / 128, S_ / 128, 1), 256, 0, stream>>>(
        h_hi, h_lo, wqkvt_h, wqkvt_l, qkv, nullptr,
        h_hi, h_lo, wqkvt_h, wqkvt_l, qkv, nullptr, S_, QKVN_, DIM_, 0);
    // 3) w1 transposes (Layout A; X is dead now)
    tsplit_kernel<<<dim3(HID_ / 32, HID_ / 32), 256, 0, stream>>>(kc_w1, w1kt_h, w1kt_l, HID_, HID_);
    tsplit_kernel<<<dim3(HID_ / 32, HID_ / 32), 256, 0, stream>>>(vc_w1, w1vt_h, w1vt_l, HID_, HID_);
    // 4) compression MLP inputs (bf16 hi/lo)
    build_cin_kernel<<<dim3(NW_, KVH_, 2), 256, 0, stream>>>(qkv, k_pos, v_pos,
        cink_h, cink_l, cinv_h, cinv_l);
    // 5) w1 (relu+bias), dual bf16x3 MFMA -> chid fp32
    gemm_mfma_kernel<<<dim3(HID_ / 128, 8, 2), 256, 0, stream>>>(
        cink_h, cink_l, w1kt_h, w1kt_l, chid_k, kc_b1,
        cinv_h, cinv_l, w1vt_h, w1vt_l, chid_v, vc_b1, MROWS_, HID_, HID_, 1);
    // 6) w2 fp32 split-K + reduce/prepend -> bf16 hi/lo compressed K (key-major) / V (d-major)
    gemm_w2sk_kernel<<<dim3(DH_ / 64, 16, 8), 256, 0, stream>>>(chid_k, chid_v, kc_w2, vc_w2, part);
    reduce_scatter_kernel<<<dim3(NWP_, KVH_, 2), 128, 0, stream>>>(part, mem_kv, kc_b2, vc_b2,
        ckh, ckl, cvth, cvtl);
    // 7) RoPE (Layout B; A is dead now)
    rope_kernel<<<dim3(S_, HEADS_ + KVH_), 64, 0, stream>>>(qkv, rq, rk);
    // 8) attention branches
    compattn_mfma_kernel<<<dim3(S_ / 16, KVH_), 256, 0, stream>>>(qkv, ckh, ckl, cvth, cvtl,
        coutb, selidx, selact);
    selattn_kernel<<<dim3(S_, KVH_), 256, 0, stream>>>(rq, rk, qkv, selidx, selact, foutb);
    swattn_kernel<<<dim3(S_, KVH_), 256, 0, stream>>>(rq, rk, qkv, swoutb);
    // 9) gating + combine (writes bf16 hi/lo of combined)
    comb_kernel<<<S_, 256, 0, stream>>>(h, w_comb, b_comb, combb);
    combine_kernel<<<(S_ * DIM_) / 256, 256, 0, stream>>>(coutb, foutb, swoutb, combb, comb_h, comb_l);
    // 10) split/transpose w_out (aliases dead coutb), then output projection
    tsplit_kernel<<<dim3(DIM_ / 32, DIM_ / 32), 256, 0, stream>>>(w_out, woutt_h, woutt_l, HEADS_ * DH_, DIM_);
    gemm_mfma_kernel<<<dim3(DIM_ / 128, S_ / 128, 1), 256, 0, stream>>>(
        comb_h, comb_l, woutt_h, woutt_l, out, nullptr,
        comb_h, comb_l, woutt_h, woutt_l, out, nullptr, S_, DIM_, HEADS_ * DH_, 0);
}

// Round 8
// 1168.882 us; speedup vs baseline: 1.6956x; 1.0284x over previous
//
#include <hip/hip_runtime.h>
#include <math.h>

#define S_ 2048
#define DIM_ 2048
#define HEADS_ 16
#define KVH_ 4
#define G_ 4
#define DH_ 128
#define NW_ 255
#define NWP_ 256
#define CBS_ 16
#define CST_ 8
#define SBS_ 16
#define NSEL_ 4
#define NF_ 128
#define SW_ 64
#define QKVN_ 3072
#define HID_ 2048
#define MROWS_ 1020   // KVH_*NW_
#define SCALE_F 0.08838834764831845f

typedef unsigned short u16;
typedef u16 u16x8 __attribute__((ext_vector_type(8)));
typedef short bf16x8 __attribute__((ext_vector_type(8)));
typedef float f32x4 __attribute__((ext_vector_type(4)));

__device__ __forceinline__ u16 f2bf(float x) {
    unsigned int u = __float_as_uint(x);
    u += 0x7fffu + ((u >> 16) & 1u);
    return (u16)(u >> 16);
}
__device__ __forceinline__ float bf2f(u16 b) {
    return __uint_as_float(((unsigned int)b) << 16);
}

// ---------------- RMSNorm (+ bf16 hi/lo split of h) ----------------
__global__ __launch_bounds__(256) void rmsnorm_kernel(const float* __restrict__ x,
    const float* __restrict__ g, float* __restrict__ h,
    u16* __restrict__ h_hi, u16* __restrict__ h_lo) {
    int s = blockIdx.x, tid = threadIdx.x;
    const float* row = x + (size_t)s * DIM_;
    float ss = 0.f;
    for (int idx = tid; idx < DIM_ / 4; idx += 256) {
        float4 v = reinterpret_cast<const float4*>(row)[idx];
        ss += v.x * v.x + v.y * v.y + v.z * v.z + v.w * v.w;
    }
    __shared__ float red[256];
    red[tid] = ss; __syncthreads();
    for (int o = 128; o > 0; o >>= 1) { if (tid < o) red[tid] += red[tid + o]; __syncthreads(); }
    float scale = 1.0f / sqrtf(red[0] / (float)DIM_ + 1e-6f);
    for (int idx = tid; idx < DIM_; idx += 256) {
        float v = row[idx] * scale * g[idx];
        size_t o = (size_t)s * DIM_ + idx;
        h[o] = v;
        u16 hb = f2bf(v);
        h_hi[o] = hb;
        h_lo[o] = f2bf(v - bf2f(hb));
    }
}

// ---------------- transpose + bf16 hi/lo split: W[K][N] -> Th/Tl[N][K] ----------------
__global__ __launch_bounds__(256) void tsplit_kernel(const float* __restrict__ W,
    u16* __restrict__ Th, u16* __restrict__ Tl, int K, int N) {
    __shared__ float t[32][33];
    int n0 = blockIdx.x * 32, k0 = blockIdx.y * 32;
    int tx = threadIdx.x & 31, ty = threadIdx.x >> 5;  // 32 x 8
#pragma unroll
    for (int j = 0; j < 4; ++j)
        t[ty + j * 8][tx] = W[(size_t)(k0 + ty + j * 8) * N + n0 + tx];
    __syncthreads();
#pragma unroll
    for (int j = 0; j < 4; ++j) {
        float v = t[tx][ty + j * 8];   // k = k0+tx, n = n0+ty+j*8
        u16 hb = f2bf(v);
        size_t o = (size_t)(n0 + ty + j * 8) * K + k0 + tx;
        Th[o] = hb;
        Tl[o] = f2bf(v - bf2f(hb));
    }
}

// ---------------- bf16x3 MFMA GEMM: C = act(Ah+Al)@(Bh+Bl)^T_layout + bias ----------------
__global__ __launch_bounds__(256, 2) void gemm_mfma_kernel(
    const u16* __restrict__ Ah0, const u16* __restrict__ Al0,
    const u16* __restrict__ Bh0, const u16* __restrict__ Bl0,
    float* __restrict__ C0, const float* __restrict__ bias0,
    const u16* __restrict__ Ah1, const u16* __restrict__ Al1,
    const u16* __restrict__ Bh1, const u16* __restrict__ Bl1,
    float* __restrict__ C1, const float* __restrict__ bias1,
    int M, int N, int K, int act) {
    const int pair = blockIdx.z;
    const u16* Ah = pair ? Ah1 : Ah0;
    const u16* Al = pair ? Al1 : Al0;
    const u16* Bh = pair ? Bh1 : Bh0;
    const u16* Bl = pair ? Bl1 : Bl0;
    float* C = pair ? C1 : C0;
    const float* bias = pair ? bias1 : bias0;

    __shared__ u16 sAh[128][56], sAl[128][56], sBh[128][56], sBl[128][56];
    const int tid = threadIdx.x;
    const int bm = blockIdx.y * 128, bn = blockIdx.x * 128;
    const int s0r = tid >> 2, sc = (tid & 3) * 8;
    const int s1r = s0r + 64;
    const int lane = tid & 63;
    const int wv = tid >> 6;
    const int wm = (wv >> 1) * 64, wn = (wv & 1) * 64;
    const int fr = lane & 15;
    const int fk = (lane >> 4) * 8;

    f32x4 acc[4][4];
#pragma unroll
    for (int i = 0; i < 4; ++i)
#pragma unroll
        for (int j = 0; j < 4; ++j) acc[i][j] = (f32x4){0.f, 0.f, 0.f, 0.f};

    const u16x8 zz = {0, 0, 0, 0, 0, 0, 0, 0};
    for (int k0 = 0; k0 < K; k0 += 32) {
        const bool g0 = (bm + s0r) < M, g1 = (bm + s1r) < M;
        const size_t a0 = (size_t)(bm + s0r) * K + k0 + sc;
        const size_t a1 = (size_t)(bm + s1r) * K + k0 + sc;
        const size_t b0 = (size_t)(bn + s0r) * K + k0 + sc;
        const size_t b1 = (size_t)(bn + s1r) * K + k0 + sc;
        u16x8 a0h = g0 ? *(const u16x8*)(Ah + a0) : zz;
        u16x8 a0l = g0 ? *(const u16x8*)(Al + a0) : zz;
        u16x8 a1h = g1 ? *(const u16x8*)(Ah + a1) : zz;
        u16x8 a1l = g1 ? *(const u16x8*)(Al + a1) : zz;
        u16x8 b0h = *(const u16x8*)(Bh + b0);
        u16x8 b0l = *(const u16x8*)(Bl + b0);
        u16x8 b1h = *(const u16x8*)(Bh + b1);
        u16x8 b1l = *(const u16x8*)(Bl + b1);
        __syncthreads();
        *(u16x8*)&sAh[s0r][sc] = a0h; *(u16x8*)&sAl[s0r][sc] = a0l;
        *(u16x8*)&sAh[s1r][sc] = a1h; *(u16x8*)&sAl[s1r][sc] = a1l;
        *(u16x8*)&sBh[s0r][sc] = b0h; *(u16x8*)&sBl[s0r][sc] = b0l;
        *(u16x8*)&sBh[s1r][sc] = b1h; *(u16x8*)&sBl[s1r][sc] = b1l;
        __syncthreads();
        bf16x8 ah[4], al[4], bh[4], bl[4];
#pragma unroll
        for (int i = 0; i < 4; ++i) {
            ah[i] = *(const bf16x8*)&sAh[wm + i * 16 + fr][fk];
            al[i] = *(const bf16x8*)&sAl[wm + i * 16 + fr][fk];
            bh[i] = *(const bf16x8*)&sBh[wn + i * 16 + fr][fk];
            bl[i] = *(const bf16x8*)&sBl[wn + i * 16 + fr][fk];
        }
#pragma unroll
        for (int i = 0; i < 4; ++i)
#pragma unroll
            for (int j = 0; j < 4; ++j) {
                acc[i][j] = __builtin_amdgcn_mfma_f32_16x16x32_bf16(ah[i], bh[j], acc[i][j], 0, 0, 0);
                acc[i][j] = __builtin_amdgcn_mfma_f32_16x16x32_bf16(ah[i], bl[j], acc[i][j], 0, 0, 0);
                acc[i][j] = __builtin_amdgcn_mfma_f32_16x16x32_bf16(al[i], bh[j], acc[i][j], 0, 0, 0);
            }
    }
    const int rq4 = (lane >> 4) * 4;
#pragma unroll
    for (int i = 0; i < 4; ++i) {
        const int rbase = bm + wm + i * 16 + rq4;
#pragma unroll
        for (int j = 0; j < 4; ++j) {
            const int col = bn + wn + j * 16 + fr;
            const float bv = bias ? bias[col] : 0.f;
#pragma unroll
            for (int r = 0; r < 4; ++r) {
                const int row = rbase + r;
                if (row < M) {
                    float v = acc[i][j][r] + bv;
                    if (act == 1) v = fmaxf(v, 0.f);
                    C[(size_t)row * N + col] = v;
                }
            }
        }
    }
}

// ---------------- dual split-K w2 GEMM (fp32): 1020x128x2048, 64x64 tile ----------------
__global__ __launch_bounds__(256) void gemm_w2sk_kernel(
    const float* __restrict__ Ak, const float* __restrict__ Av,
    const float* __restrict__ Bk, const float* __restrict__ Bv,
    float* __restrict__ part) {
    const int pair = blockIdx.z >> 2, ks = blockIdx.z & 3;
    const float* A = pair ? Av : Ak;   // 1020 x 2048
    const float* B = pair ? Bv : Bk;   // 2048 x 128
    __shared__ float As[16][64];
    __shared__ float Bs[16][64];
    const int tid = threadIdx.x;
    const int bm = blockIdx.y * 64, bn = blockIdx.x * 64;
    const int tx = tid & 15, ty = tid >> 4;
    const int ar = tid >> 2, ac = (tid & 3) << 2;
    const int br = tid >> 4, bc = (tid & 15) << 2;
    const int k_lo = ks * 512;
    float acc[4][4] = {};
    for (int k0 = k_lo; k0 < k_lo + 512; k0 += 16) {
        float4 av = make_float4(0.f, 0.f, 0.f, 0.f);
        if (bm + ar < MROWS_) av = *reinterpret_cast<const float4*>(A + (size_t)(bm + ar) * HID_ + k0 + ac);
        float4 bv = *reinterpret_cast<const float4*>(B + (size_t)(k0 + br) * DH_ + bn + bc);
        __syncthreads();
        As[ac + 0][ar] = av.x; As[ac + 1][ar] = av.y; As[ac + 2][ar] = av.z; As[ac + 3][ar] = av.w;
        *reinterpret_cast<float4*>(&Bs[br][bc]) = bv;
        __syncthreads();
#pragma unroll
        for (int k = 0; k < 16; ++k) {
            float4 a = *reinterpret_cast<const float4*>(&As[k][ty << 2]);
            float4 b = *reinterpret_cast<const float4*>(&Bs[k][tx << 2]);
            float aa[4] = {a.x, a.y, a.z, a.w};
            float bb[4] = {b.x, b.y, b.z, b.w};
#pragma unroll
            for (int i = 0; i < 4; ++i)
#pragma unroll
                for (int j = 0; j < 4; ++j) acc[i][j] += aa[i] * bb[j];
        }
        __syncthreads();
    }
    const int row0 = bm + (ty << 2), col0 = bn + (tx << 2);
    float* dst = part + ((size_t)(pair * 4 + ks) * MROWS_) * DH_;
#pragma unroll
    for (int i = 0; i < 4; ++i) {
        int r = row0 + i;
        if (r < MROWS_)
            *reinterpret_cast<float4*>(dst + (size_t)r * DH_ + col0) =
                make_float4(acc[i][0], acc[i][1], acc[i][2], acc[i][3]);
    }
}

// ---------- reduce split-K partials + bias, prepend mem row; emit bf16 hi/lo ----------
// pair=0: ck -> ckh/ckl [kvh][256][128] (key-major). pair=1: cv -> cvth/cvtl [kvh][128][256] (d-major).
__global__ __launch_bounds__(128) void reduce_scatter_kernel(
    const float* __restrict__ part, const float* __restrict__ mem,
    const float* __restrict__ bk, const float* __restrict__ bv,
    u16* __restrict__ ckh, u16* __restrict__ ckl,
    u16* __restrict__ cvth, u16* __restrict__ cvtl) {
    const int r = blockIdx.x, kvh = blockIdx.y, pair = blockIdx.z, d = threadIdx.x;
    float v;
    if (r == 0) {
        v = mem[(size_t)pair * KVH_ * DH_ + kvh * DH_ + d];
    } else {
        const size_t row = (size_t)kvh * NW_ + (r - 1);
        const float* p0 = part + ((size_t)pair * 4 * MROWS_ + row) * DH_ + d;
        const size_t stride = (size_t)MROWS_ * DH_;
        v = p0[0] + p0[stride] + p0[2 * stride] + p0[3 * stride];
        v += (pair ? bv[d] : bk[d]);
    }
    u16 hb = f2bf(v);
    u16 lb = f2bf(v - bf2f(hb));
    if (pair == 0) {
        size_t o = ((size_t)kvh * NWP_ + r) * DH_ + d;
        ckh[o] = hb; ckl[o] = lb;
    } else {
        size_t o = ((size_t)kvh * DH_ + d) * NWP_ + r;
        cvth[o] = hb; cvtl[o] = lb;
    }
}

// ---------------- build compression-MLP inputs (bf16 hi/lo), k and v ----------------
__global__ __launch_bounds__(256) void build_cin_kernel(const float* __restrict__ qkv,
    const float* __restrict__ k_pos, const float* __restrict__ v_pos,
    u16* __restrict__ cink_h, u16* __restrict__ cink_l,
    u16* __restrict__ cinv_h, u16* __restrict__ cinv_l) {
    int w = blockIdx.x, kvh = blockIdx.y, pair = blockIdx.z, tid = threadIdx.x;
    const float* posw = pair ? v_pos : k_pos;
    u16* ch = pair ? cinv_h : cink_h;
    u16* cl = pair ? cinv_l : cink_l;
    const int col_off = pair ? (DIM_ + KVH_ * DH_) : DIM_;
    for (int idx = tid; idx < CBS_ * DH_; idx += 256) {
        int t = idx >> 7, d = idx & 127;
        int srow = w * CST_ + t;
        float v = qkv[(size_t)srow * QKVN_ + col_off + kvh * DH_ + d] + posw[(kvh * CBS_ + t) * DH_ + d];
        size_t o = ((size_t)kvh * NW_ + w) * HID_ + idx;
        u16 hb = f2bf(v);
        ch[o] = hb;
        cl[o] = f2bf(v - bf2f(hb));
    }
}

// ---------------- RoPE for q (16 heads) and k (4 heads) ----------------
__global__ __launch_bounds__(64) void rope_kernel(const float* __restrict__ qkv,
    float* __restrict__ rq, float* __restrict__ rk) {
    int s = blockIdx.x, head = blockIdx.y, i = threadIdx.x;
    float inv = 1.0f / powf(10000.0f, (float)i / 64.0f);
    float ang = (float)s * inv;
    float c = cosf(ang), sn = sinf(ang);
    const float* src; float* dst;
    if (head < HEADS_) {
        src = qkv + (size_t)s * QKVN_ + head * DH_;
        dst = rq + ((size_t)head * S_ + s) * DH_;
    } else {
        int kvh = head - HEADS_;
        src = qkv + (size_t)s * QKVN_ + DIM_ + kvh * DH_;
        dst = rk + ((size_t)kvh * S_ + s) * DH_;
    }
    float t1 = src[2 * i], t2 = src[2 * i + 1];
    dst[2 * i] = t1 * c - t2 * sn;
    dst[2 * i + 1] = t1 * sn + t2 * c;
}

// ------- compression attention via MFMA: 16 queries x 4 g per block + top-k -------
__global__ __launch_bounds__(256) void compattn_mfma_kernel(
    const float* __restrict__ qkv,
    const u16* __restrict__ ckh, const u16* __restrict__ ckl,
    const u16* __restrict__ cvth, const u16* __restrict__ cvtl,
    float* __restrict__ coutb, int* __restrict__ selidx, int* __restrict__ selact) {
    const int s0 = blockIdx.x * 16, kvh = blockIdx.y;
    const int tid = threadIdx.x, lane = tid & 63, w = tid >> 6;
    const int fr = lane & 15, fq = lane >> 4;
    __shared__ u16 attn_h[4][16][264];
    __shared__ u16 attn_l[4][16][264];
    __shared__ float bimpS[16][128];

    // Q fragments: rows = 16 queries, head = kvh*G + w
    bf16x8 qh[4], ql[4];
    {
        const float* qbase = qkv + (size_t)(s0 + fr) * QKVN_ + (kvh * G_ + w) * DH_;
#pragma unroll
        for (int kk = 0; kk < 4; ++kk) {
            int d0 = kk * 32 + fq * 8;
            float4 v0 = *reinterpret_cast<const float4*>(qbase + d0);
            float4 v1 = *reinterpret_cast<const float4*>(qbase + d0 + 4);
            float vv[8] = {v0.x, v0.y, v0.z, v0.w, v1.x, v1.y, v1.z, v1.w};
            u16x8 hh, ll;
#pragma unroll
            for (int j = 0; j < 8; ++j) {
                u16 hb = f2bf(vv[j]);
                hh[j] = hb; ll[j] = f2bf(vv[j] - bf2f(hb));
            }
            qh[kk] = *(bf16x8*)&hh; ql[kk] = *(bf16x8*)&ll;
        }
    }
    // QK^T: 16 column tiles of 16 keys each (256 keys total)
    f32x4 sc[16];
#pragma unroll
    for (int ct = 0; ct < 16; ++ct) {
        f32x4 acc = (f32x4){0.f, 0.f, 0.f, 0.f};
        const u16* kbh = ckh + ((size_t)kvh * NWP_ + ct * 16 + fr) * DH_ + fq * 8;
        const u16* kbl = ckl + ((size_t)kvh * NWP_ + ct * 16 + fr) * DH_ + fq * 8;
#pragma unroll
        for (int kk = 0; kk < 4; ++kk) {
            bf16x8 bh = *(const bf16x8*)(kbh + kk * 32);
            bf16x8 bl = *(const bf16x8*)(kbl + kk * 32);
            acc = __builtin_amdgcn_mfma_f32_16x16x32_bf16(qh[kk], bh, acc, 0, 0, 0);
            acc = __builtin_amdgcn_mfma_f32_16x16x32_bf16(ql[kk], bh, acc, 0, 0, 0);
            acc = __builtin_amdgcn_mfma_f32_16x16x32_bf16(qh[kk], bl, acc, 0, 0, 0);
        }
        sc[ct] = acc;
    }
    // mask + scale + in-register softmax (row = query fq*4+ri; col = ct*16+fr)
    float mrow[4], rsum[4], rinv[4];
#pragma unroll
    for (int ri = 0; ri < 4; ++ri) mrow[ri] = -INFINITY;
#pragma unroll
    for (int ct = 0; ct < 16; ++ct) {
        int j = ct * 16 + fr;
#pragma unroll
        for (int ri = 0; ri < 4; ++ri) {
            int s = s0 + fq * 4 + ri;
            bool vis = (j == 0) || (s > (j - 1) * CST_ + CBS_ - 1);
            float v = vis ? sc[ct][ri] * SCALE_F : -INFINITY;
            sc[ct][ri] = v;
            mrow[ri] = fmaxf(mrow[ri], v);
        }
    }
#pragma unroll
    for (int off = 8; off >= 1; off >>= 1)
#pragma unroll
        for (int ri = 0; ri < 4; ++ri) mrow[ri] = fmaxf(mrow[ri], __shfl_xor(mrow[ri], off));
#pragma unroll
    for (int ri = 0; ri < 4; ++ri) rsum[ri] = 0.f;
#pragma unroll
    for (int ct = 0; ct < 16; ++ct)
#pragma unroll
        for (int ri = 0; ri < 4; ++ri) {
            float e = expf(sc[ct][ri] - mrow[ri]);
            sc[ct][ri] = e; rsum[ri] += e;
        }
#pragma unroll
    for (int off = 8; off >= 1; off >>= 1)
#pragma unroll
        for (int ri = 0; ri < 4; ++ri) rsum[ri] += __shfl_xor(rsum[ri], off);
#pragma unroll
    for (int ri = 0; ri < 4; ++ri) rinv[ri] = 1.f / rsum[ri];
    // attn -> LDS (bf16 hi/lo)
#pragma unroll
    for (int ct = 0; ct < 16; ++ct)
#pragma unroll
        for (int ri = 0; ri < 4; ++ri) {
            float a = sc[ct][ri] * rinv[ri];
            u16 hb = f2bf(a);
            attn_h[w][fq * 4 + ri][ct * 16 + fr] = hb;
            attn_l[w][fq * 4 + ri][ct * 16 + fr] = f2bf(a - bf2f(hb));
        }
    __syncthreads();
    // block importance: bimp[sq][f] = (1/8) * sum_g (attn[2f+1] + attn[2f+2])
    for (int idx = tid; idx < 16 * 128; idx += 256) {
        int sq = idx >> 7, f = idx & 127;
        int j1 = 2 * f + 1, j2 = 2 * f + 2;
        float a = 0.f;
#pragma unroll
        for (int g = 0; g < 4; ++g) {
            a += bf2f(attn_h[g][sq][j1]) + bf2f(attn_l[g][sq][j1]);
            if (f < 127) a += bf2f(attn_h[g][sq][j2]) + bf2f(attn_l[g][sq][j2]);
        }
        float v = a * 0.125f;
        bimpS[sq][f] = (f < (s0 >> 4)) ? v : -1.0f;
    }
    __syncthreads();
    // serial top-4 per query (strict >, lowest index wins)
    if (tid < 16) {
        int s = s0 + tid;
        int base = (kvh * S_ + s) * NSEL_;
        for (int kk = 0; kk < NSEL_; ++kk) {
            float best = -1e30f; int bi = 0;
            for (int f = 0; f < NF_; ++f) {
                float v = bimpS[tid][f];
                if (v > best) { best = v; bi = f; }
            }
            bimpS[tid][bi] = -1e31f;
            selidx[base + kk] = bi;
            selact[base + kk] = (best > 0.f) ? 1 : 0;
        }
    }
    // PV: out[16 x 128] = attn[16 x 256] @ cv[256 x 128] (cv stored d-major)
    f32x4 po[8];
#pragma unroll
    for (int dt = 0; dt < 8; ++dt) po[dt] = (f32x4){0.f, 0.f, 0.f, 0.f};
#pragma unroll
    for (int jc = 0; jc < 8; ++jc) {
        bf16x8 ah = *(const bf16x8*)&attn_h[w][fr][jc * 32 + fq * 8];
        bf16x8 al = *(const bf16x8*)&attn_l[w][fr][jc * 32 + fq * 8];
#pragma unroll
        for (int dt = 0; dt < 8; ++dt) {
            const u16* vbh = cvth + ((size_t)kvh * DH_ + dt * 16 + fr) * NWP_ + jc * 32 + fq * 8;
            const u16* vbl = cvtl + ((size_t)kvh * DH_ + dt * 16 + fr) * NWP_ + jc * 32 + fq * 8;
            bf16x8 bh = *(const bf16x8*)vbh;
            bf16x8 bl = *(const bf16x8*)vbl;
            po[dt] = __builtin_amdgcn_mfma_f32_16x16x32_bf16(ah, bh, po[dt], 0, 0, 0);
            po[dt] = __builtin_amdgcn_mfma_f32_16x16x32_bf16(al, bh, po[dt], 0, 0, 0);
            po[dt] = __builtin_amdgcn_mfma_f32_16x16x32_bf16(ah, bl, po[dt], 0, 0, 0);
        }
    }
#pragma unroll
    for (int dt = 0; dt < 8; ++dt)
#pragma unroll
        for (int ri = 0; ri < 4; ++ri) {
            int sq = fq * 4 + ri;
            coutb[(((size_t)(kvh * G_ + w)) * S_ + s0 + sq) * DH_ + dt * 16 + fr] = po[dt][ri];
        }
}

// ---------------- selection attention (J = 80 keys), split-dot + LDS-staged V ----------------
__global__ __launch_bounds__(256) void selattn_kernel(
    const float* __restrict__ rq, const float* __restrict__ rk, const float* __restrict__ qkv,
    const int* __restrict__ selidx, const int* __restrict__ selact, float* __restrict__ foutb) {
    const int s = blockIdx.x, kvh = blockIdx.y, tid = threadIdx.x;
    const int J = (NSEL_ + 1) * SBS_;  // 80
    __shared__ float qs[G_][DH_];
    __shared__ float kl[80][DH_ + 1];  // phase 1: K_sel, phase 2: V_sel
    __shared__ float sc[G_][80];
    __shared__ int posb[80];
    __shared__ int maskb[80];
    if (tid < J) {
        int b = tid >> 4, t = tid & 15;
        int p, ok;
        if (b < NSEL_) {
            int base = (kvh * S_ + s) * NSEL_ + b;
            int f = selidx[base];
            p = f * SBS_ + t;
            ok = selact[base] && (p <= s);
        } else {
            p = (s >> 4) * SBS_ + t;
            ok = (p <= s);
        }
        posb[tid] = p; maskb[tid] = ok;
    }
    for (int idx = tid; idx < G_ * DH_; idx += 256) {
        int g = idx >> 7, d = idx & 127;
        qs[g][d] = rq[(((size_t)(kvh * G_ + g)) * S_ + s) * DH_ + d];
    }
    __syncthreads();
    for (int idx = tid; idx < J * DH_; idx += 256) {
        int r = idx >> 7, d = idx & 127;
        kl[r][d] = rk[((size_t)kvh * S_ + posb[r]) * DH_ + d];
    }
    __syncthreads();
    // scores: each dot split across 4 lanes (32-FMA partials + shfl combine)
    for (int t = tid; t < G_ * J * 4; t += 256) {
        int q4 = t & 3;
        int rest = t >> 2;
        int g = rest / J, j = rest % J;
        const float* qp = &qs[g][q4 * 32];
        const float* kp = &kl[j][q4 * 32];
        float a = 0.f;
#pragma unroll
        for (int d = 0; d < 32; ++d) a += qp[d] * kp[d];
        a += __shfl_xor(a, 1);
        a += __shfl_xor(a, 2);
        if (q4 == 0) sc[g][j] = maskb[j] ? a * SCALE_F : -INFINITY;
    }
    __syncthreads();
    const int wv = tid >> 6, ln = tid & 63;
    float v0 = sc[wv][ln];
    float v1 = (ln < J - 64) ? sc[wv][64 + ln] : -INFINITY;
    float m = fmaxf(v0, v1);
#pragma unroll
    for (int off = 32; off > 0; off >>= 1) m = fmaxf(m, __shfl_xor(m, off));
    float e0 = expf(v0 - m);
    float e1 = (ln < J - 64) ? expf(v1 - m) : 0.f;
    float ssum = e0 + e1;
#pragma unroll
    for (int off = 32; off > 0; off >>= 1) ssum += __shfl_xor(ssum, off);
    float inv = 1.f / ssum;
    sc[wv][ln] = e0 * inv;
    if (ln < J - 64) sc[wv][64 + ln] = e1 * inv;
    __syncthreads();
    // stage V_sel into the dead K buffer
    for (int idx = tid; idx < J * DH_; idx += 256) {
        int r = idx >> 7, d = idx & 127;
        kl[r][d] = qkv[(size_t)posb[r] * QKVN_ + (DIM_ + KVH_ * DH_) + kvh * DH_ + d];
    }
    __syncthreads();
    for (int it = tid; it < G_ * DH_; it += 256) {
        int g = it >> 7, d = it & 127;
        float a = 0.f;
#pragma unroll 8
        for (int j = 0; j < J; ++j) a += sc[g][j] * kl[j][d];
        foutb[(((size_t)(kvh * G_ + g)) * S_ + s) * DH_ + d] = a;
    }
}

// ---------------- sliding window attention (J = 65 keys), split-dot + LDS-staged V ----------------
__global__ __launch_bounds__(256) void swattn_kernel(
    const float* __restrict__ rq, const float* __restrict__ rk, const float* __restrict__ qkv,
    float* __restrict__ swoutb) {
    const int s = blockIdx.x, kvh = blockIdx.y, tid = threadIdx.x;
    const int J = SW_ + 1;  // 65
    __shared__ float qs[G_][DH_];
    __shared__ float kl[65][DH_ + 1];  // phase 1: K, phase 2: V
    __shared__ float sc[G_][65];
    for (int idx = tid; idx < G_ * DH_; idx += 256) {
        int g = idx >> 7, d = idx & 127;
        qs[g][d] = rq[(((size_t)(kvh * G_ + g)) * S_ + s) * DH_ + d];
    }
    for (int idx = tid; idx < J * DH_; idx += 256) {
        int r = idx >> 7, d = idx & 127;
        int p = s - SW_ + r;
        kl[r][d] = (p >= 0) ? rk[((size_t)kvh * S_ + p) * DH_ + d] : 0.f;
    }
    __syncthreads();
    // scores: split each 128-dot across 4 lanes
    for (int t = tid; t < G_ * J * 4; t += 256) {
        int q4 = t & 3;
        int rest = t >> 2;
        int g = rest / J, j = rest % J;
        const float* qp = &qs[g][q4 * 32];
        const float* kp = &kl[j][q4 * 32];
        float a = 0.f;
#pragma unroll
        for (int d = 0; d < 32; ++d) a += qp[d] * kp[d];
        a += __shfl_xor(a, 1);
        a += __shfl_xor(a, 2);
        if (q4 == 0) {
            int p = s - SW_ + j;
            sc[g][j] = (p >= 0) ? a * SCALE_F : -INFINITY;
        }
    }
    __syncthreads();
    const int wv = tid >> 6, ln = tid & 63;
    float v0 = sc[wv][ln];
    float v1 = (ln < J - 64) ? sc[wv][64 + ln] : -INFINITY;
    float m = fmaxf(v0, v1);
#pragma unroll
    for (int off = 32; off > 0; off >>= 1) m = fmaxf(m, __shfl_xor(m, off));
    float e0 = expf(v0 - m);
    float e1 = (ln < J - 64) ? expf(v1 - m) : 0.f;
    float ssum = e0 + e1;
#pragma unroll
    for (int off = 32; off > 0; off >>= 1) ssum += __shfl_xor(ssum, off);
    float inv = 1.f / ssum;
    sc[wv][ln] = e0 * inv;
    if (ln < J - 64) sc[wv][64 + ln] = e1 * inv;
    __syncthreads();
    // stage V into the dead K buffer (clamped row for p<0; weight is 0 there)
    for (int idx = tid; idx < J * DH_; idx += 256) {
        int r = idx >> 7, d = idx & 127;
        int p = s - SW_ + r;
        int pc = p < 0 ? 0 : p;
        kl[r][d] = qkv[(size_t)pc * QKVN_ + (DIM_ + KVH_ * DH_) + kvh * DH_ + d];
    }
    __syncthreads();
    for (int it = tid; it < G_ * DH_; it += 256) {
        int g = it >> 7, d = it & 127;
        float a = 0.f;
#pragma unroll 8
        for (int j = 0; j < J; ++j) a += sc[g][j] * kl[j][d];
        swoutb[(((size_t)(kvh * G_ + g)) * S_ + s) * DH_ + d] = a;
    }
}

// ---------------- gating head ----------------
__global__ __launch_bounds__(256) void comb_kernel(const float* __restrict__ h,
    const float* __restrict__ w_comb, const float* __restrict__ b_comb, float* __restrict__ comb) {
    int s = blockIdx.x, tid = threadIdx.x;
    __shared__ float hrow[DIM_];
    for (int idx = tid; idx < DIM_; idx += 256) hrow[idx] = h[(size_t)s * DIM_ + idx];
    __syncthreads();
    if (tid < 192) {
        int o = tid >> 2, p = tid & 3;
        float a = 0.f;
        for (int d = p; d < DIM_; d += 4) a += hrow[d] * w_comb[(size_t)d * 48 + o];
        a += __shfl_xor(a, 1);
        a += __shfl_xor(a, 2);
        if (p == 0) comb[(size_t)s * 48 + o] = 1.f / (1.f + expf(-(a + b_comb[o])));
    }
}

// ---------------- combine branches with gates -> bf16 hi/lo ----------------
__global__ __launch_bounds__(256) void combine_kernel(const float* __restrict__ c0b,
    const float* __restrict__ c1b, const float* __restrict__ c2b,
    const float* __restrict__ comb, u16* __restrict__ comb_h, u16* __restrict__ comb_l) {
    size_t i = (size_t)blockIdx.x * 256 + threadIdx.x;
    int s = (int)(i >> 11);
    int hd = (int)(i & 2047);
    int hh = hd >> 7;
    int d = hd & 127;
    size_t src = ((size_t)hh * S_ + s) * DH_ + d;
    const float* cb = comb + (size_t)s * 48 + hh * 3;
    float v = c0b[src] * cb[0] + c1b[src] * cb[1] + c2b[src] * cb[2];
    u16 hb = f2bf(v);
    comb_h[i] = hb;
    comb_l[i] = f2bf(v - bf2f(hb));
}

extern "C" void kernel_launch(void* const* d_in, const int* in_sizes, int n_in,
                              void* d_out, int out_size, void* d_ws, size_t ws_size,
                              hipStream_t stream) {
    const float* x      = (const float*)d_in[0];
    const float* g_norm = (const float*)d_in[1];
    const float* w_qkv  = (const float*)d_in[2];
    const float* k_pos  = (const float*)d_in[3];
    const float* v_pos  = (const float*)d_in[4];
    const float* mem_kv = (const float*)d_in[5];
    const float* kc_w1  = (const float*)d_in[6];
    const float* kc_b1  = (const float*)d_in[7];
    const float* kc_w2  = (const float*)d_in[8];
    const float* kc_b2  = (const float*)d_in[9];
    const float* vc_w1  = (const float*)d_in[10];
    const float* vc_b1  = (const float*)d_in[11];
    const float* vc_w2  = (const float*)d_in[12];
    const float* vc_b2  = (const float*)d_in[13];
    const float* w_comb = (const float*)d_in[14];
    const float* b_comb = (const float*)d_in[15];
    const float* w_out  = (const float*)d_in[16];
    float* out = (float*)d_out;
    float* ws = (float*)d_ws;

    // Persistent: h(4194304) qkv(6291456) + compressed-kv bf16 arrays (262144 fl worth)
    float* h   = ws;
    float* qkv = h + 4194304;
    u16* ckh  = (u16*)(qkv + 6291456);   // 131,072 u16 each
    u16* ckl  = ckh + 131072;
    u16* cvth = ckl + 131072;
    u16* cvtl = cvth + 131072;
    float* uni = qkv + 6291456 + 262144; // union region, 3 sequential layouts

    // Layout X (steps 1-2): h splits + transposed/split w_qkv
    u16* h_hi    = (u16*)uni;            // 4,194,304 u16
    u16* h_lo    = h_hi + 4194304;
    u16* wqkvt_h = h_lo + 4194304;       // 6,291,456 u16
    u16* wqkvt_l = wqkvt_h + 6291456;

    // Layout A (steps 3-6): w1 transposes + cin splits + chid + part
    u16* w1kt_h = (u16*)uni;             // 4,194,304 u16 each
    u16* w1kt_l = w1kt_h + 4194304;
    u16* w1vt_h = w1kt_l + 4194304;
    u16* w1vt_l = w1vt_h + 4194304;
    u16* cink_h = w1vt_l + 4194304;      // 2,088,960 u16 each
    u16* cink_l = cink_h + 2088960;
    u16* cinv_h = cink_l + 2088960;
    u16* cinv_l = cinv_h + 2088960;
    float* chid_k = uni + 12566528;      // 2,088,960 fl each
    float* chid_v = chid_k + 2088960;
    float* part   = chid_v + 2088960;    // 1,044,480 fl

    // Layout B (steps 7+): attention buffers
    float* rq     = uni;                 // 4,194,304
    float* rk     = rq + 4194304;        // 1,048,576
    float* coutb  = rk + 1048576;        // 4,194,304 (aliased by woutt after combine)
    float* foutb  = coutb + 4194304;     // 4,194,304
    float* swoutb = foutb + 4194304;     // 4,194,304
    float* combb  = swoutb + 4194304;    // 98,304
    u16* comb_h   = (u16*)(combb + 98304);      // 4,194,304 u16
    u16* comb_l   = comb_h + 4194304;           // 4,194,304 u16
    int* selidx   = (int*)(comb_l + 4194304);   // 32,768 ints
    int* selact   = selidx + 32768;             // 32,768 ints
    u16* woutt_h  = (u16*)coutb;         // 4,194,304 u16 each (fits in dead coutb)
    u16* woutt_l  = woutt_h + 4194304;

    // 1) RMSNorm + h split
    rmsnorm_kernel<<<S_, 256, 0, stream>>>(x, g_norm, h, h_hi, h_lo);
    // 2) split/transpose w_qkv, then qkv projection via bf16x3 MFMA
    tsplit_kernel<<<dim3(QKVN_ / 32, DIM_ / 32), 256, 0, stream>>>(w_qkv, wqkvt_h, wqkvt_l, DIM_, QKVN_);
    gemm_mfma_kernel<<<dim3(QKVN_ / 128, S_ / 128, 1), 256, 0, stream>>>(
        h_hi, h_lo, wqkvt_h, wqkvt_l, qkv, nullptr,
        h_hi, h_lo, wqkvt_h, wqkvt_l, qkv, nullptr, S_, QKVN_, DIM_, 0);
    // 3) w1 transposes (Layout A; X is dead now)
    tsplit_kernel<<<dim3(HID_ / 32, HID_ / 32), 256, 0, stream>>>(kc_w1, w1kt_h, w1kt_l, HID_, HID_);
    tsplit_kernel<<<dim3(HID_ / 32, HID_ / 32), 256, 0, stream>>>(vc_w1, w1vt_h, w1vt_l, HID_, HID_);
    // 4) compression MLP inputs (bf16 hi/lo)
    build_cin_kernel<<<dim3(NW_, KVH_, 2), 256, 0, stream>>>(qkv, k_pos, v_pos,
        cink_h, cink_l, cinv_h, cinv_l);
    // 5) w1 (relu+bias), dual bf16x3 MFMA -> chid fp32
    gemm_mfma_kernel<<<dim3(HID_ / 128, 8, 2), 256, 0, stream>>>(
        cink_h, cink_l, w1kt_h, w1kt_l, chid_k, kc_b1,
        cinv_h, cinv_l, w1vt_h, w1vt_l, chid_v, vc_b1, MROWS_, HID_, HID_, 1);
    // 6) w2 fp32 split-K + reduce/prepend -> bf16 hi/lo compressed K (key-major) / V (d-major)
    gemm_w2sk_kernel<<<dim3(DH_ / 64, 16, 8), 256, 0, stream>>>(chid_k, chid_v, kc_w2, vc_w2, part);
    reduce_scatter_kernel<<<dim3(NWP_, KVH_, 2), 128, 0, stream>>>(part, mem_kv, kc_b2, vc_b2,
        ckh, ckl, cvth, cvtl);
    // 7) RoPE (Layout B; A is dead now)
    rope_kernel<<<dim3(S_, HEADS_ + KVH_), 64, 0, stream>>>(qkv, rq, rk);
    // 8) attention branches
    compattn_mfma_kernel<<<dim3(S_ / 16, KVH_), 256, 0, stream>>>(qkv, ckh, ckl, cvth, cvtl,
        coutb, selidx, selact);
    selattn_kernel<<<dim3(S_, KVH_), 256, 0, stream>>>(rq, rk, qkv, selidx, selact, foutb);
    swattn_kernel<<<dim3(S_, KVH_), 256, 0, stream>>>(rq, rk, qkv, swoutb);
    // 9) gating + combine (writes bf16 hi/lo of combined)
    comb_kernel<<<S_, 256, 0, stream>>>(h, w_comb, b_comb, combb);
    combine_kernel<<<(S_ * DIM_) / 256, 256, 0, stream>>>(coutb, foutb, swoutb, combb, comb_h, comb_l);
    // 10) split/transpose w_out (aliases dead coutb), then output projection
    tsplit_kernel<<<dim3(DIM_ / 32, DIM_ / 32), 256, 0, stream>>>(w_out, woutt_h, woutt_l, HEADS_ * DH_, DIM_);
    gemm_mfma_kernel<<<dim3(DIM_ / 128, S_ / 128, 1), 256, 0, stream>>>(
        comb_h, comb_l, woutt_h, woutt_l, out, nullptr,
        comb_h, comb_l, woutt_h, woutt_l, out, nullptr, S_, DIM_, HEADS_ * DH_, 0);
}

// Round 9
// 1014.961 us; speedup vs baseline: 1.9527x; 1.1517x over previous
//
#include <hip/hip_runtime.h>
#include <math.h>

#define S_ 2048
#define DIM_ 2048
#define HEADS_ 16
#define KVH_ 4
#define G_ 4
#define DH_ 128
#define NW_ 255
#define NWP_ 256
#define CBS_ 16
#define CST_ 8
#define SBS_ 16
#define NSEL_ 4
#define NF_ 128
#define SW_ 64
#define QKVN_ 3072
#define HID_ 2048
#define MROWS_ 1020   // KVH_*NW_
#define SCALE_F 0.08838834764831845f

typedef unsigned short u16;
typedef u16 u16x8 __attribute__((ext_vector_type(8)));
typedef short bf16x8 __attribute__((ext_vector_type(8)));
typedef float f32x4 __attribute__((ext_vector_type(4)));

__device__ __forceinline__ u16 f2bf(float x) {
    unsigned int u = __float_as_uint(x);
    u += 0x7fffu + ((u >> 16) & 1u);
    return (u16)(u >> 16);
}
__device__ __forceinline__ float bf2f(u16 b) {
    return __uint_as_float(((unsigned int)b) << 16);
}

// ---------------- RMSNorm (+ bf16 hi/lo split of h) ----------------
__global__ __launch_bounds__(256) void rmsnorm_kernel(const float* __restrict__ x,
    const float* __restrict__ g, float* __restrict__ h,
    u16* __restrict__ h_hi, u16* __restrict__ h_lo) {
    int s = blockIdx.x, tid = threadIdx.x;
    const float* row = x + (size_t)s * DIM_;
    float ss = 0.f;
    for (int idx = tid; idx < DIM_ / 4; idx += 256) {
        float4 v = reinterpret_cast<const float4*>(row)[idx];
        ss += v.x * v.x + v.y * v.y + v.z * v.z + v.w * v.w;
    }
    __shared__ float red[256];
    red[tid] = ss; __syncthreads();
    for (int o = 128; o > 0; o >>= 1) { if (tid < o) red[tid] += red[tid + o]; __syncthreads(); }
    float scale = 1.0f / sqrtf(red[0] / (float)DIM_ + 1e-6f);
    for (int idx = tid; idx < DIM_; idx += 256) {
        float v = row[idx] * scale * g[idx];
        size_t o = (size_t)s * DIM_ + idx;
        h[o] = v;
        u16 hb = f2bf(v);
        h_hi[o] = hb;
        h_lo[o] = f2bf(v - bf2f(hb));
    }
}

// ---------------- transpose + bf16 hi/lo split: W[K][N] -> Th/Tl[N][K] ----------------
__global__ __launch_bounds__(256) void tsplit_kernel(const float* __restrict__ W,
    u16* __restrict__ Th, u16* __restrict__ Tl, int K, int N) {
    __shared__ float t[32][33];
    int n0 = blockIdx.x * 32, k0 = blockIdx.y * 32;
    int tx = threadIdx.x & 31, ty = threadIdx.x >> 5;  // 32 x 8
#pragma unroll
    for (int j = 0; j < 4; ++j)
        t[ty + j * 8][tx] = W[(size_t)(k0 + ty + j * 8) * N + n0 + tx];
    __syncthreads();
#pragma unroll
    for (int j = 0; j < 4; ++j) {
        float v = t[tx][ty + j * 8];   // k = k0+tx, n = n0+ty+j*8
        u16 hb = f2bf(v);
        size_t o = (size_t)(n0 + ty + j * 8) * K + k0 + tx;
        Th[o] = hb;
        Tl[o] = f2bf(v - bf2f(hb));
    }
}

// ---------------- bf16x3 MFMA GEMM: C = act(Ah+Al)@(Bh+Bl)^T_layout + bias ----------------
__global__ __launch_bounds__(256, 2) void gemm_mfma_kernel(
    const u16* __restrict__ Ah0, const u16* __restrict__ Al0,
    const u16* __restrict__ Bh0, const u16* __restrict__ Bl0,
    float* __restrict__ C0, const float* __restrict__ bias0,
    const u16* __restrict__ Ah1, const u16* __restrict__ Al1,
    const u16* __restrict__ Bh1, const u16* __restrict__ Bl1,
    float* __restrict__ C1, const float* __restrict__ bias1,
    int M, int N, int K, int act) {
    const int pair = blockIdx.z;
    const u16* Ah = pair ? Ah1 : Ah0;
    const u16* Al = pair ? Al1 : Al0;
    const u16* Bh = pair ? Bh1 : Bh0;
    const u16* Bl = pair ? Bl1 : Bl0;
    float* C = pair ? C1 : C0;
    const float* bias = pair ? bias1 : bias0;

    __shared__ u16 sAh[128][56], sAl[128][56], sBh[128][56], sBl[128][56];
    const int tid = threadIdx.x;
    const int bm = blockIdx.y * 128, bn = blockIdx.x * 128;
    const int s0r = tid >> 2, sc = (tid & 3) * 8;
    const int s1r = s0r + 64;
    const int lane = tid & 63;
    const int wv = tid >> 6;
    const int wm = (wv >> 1) * 64, wn = (wv & 1) * 64;
    const int fr = lane & 15;
    const int fk = (lane >> 4) * 8;

    f32x4 acc[4][4];
#pragma unroll
    for (int i = 0; i < 4; ++i)
#pragma unroll
        for (int j = 0; j < 4; ++j) acc[i][j] = (f32x4){0.f, 0.f, 0.f, 0.f};

    const u16x8 zz = {0, 0, 0, 0, 0, 0, 0, 0};
    for (int k0 = 0; k0 < K; k0 += 32) {
        const bool g0 = (bm + s0r) < M, g1 = (bm + s1r) < M;
        const size_t a0 = (size_t)(bm + s0r) * K + k0 + sc;
        const size_t a1 = (size_t)(bm + s1r) * K + k0 + sc;
        const size_t b0 = (size_t)(bn + s0r) * K + k0 + sc;
        const size_t b1 = (size_t)(bn + s1r) * K + k0 + sc;
        u16x8 a0h = g0 ? *(const u16x8*)(Ah + a0) : zz;
        u16x8 a0l = g0 ? *(const u16x8*)(Al + a0) : zz;
        u16x8 a1h = g1 ? *(const u16x8*)(Ah + a1) : zz;
        u16x8 a1l = g1 ? *(const u16x8*)(Al + a1) : zz;
        u16x8 b0h = *(const u16x8*)(Bh + b0);
        u16x8 b0l = *(const u16x8*)(Bl + b0);
        u16x8 b1h = *(const u16x8*)(Bh + b1);
        u16x8 b1l = *(const u16x8*)(Bl + b1);
        __syncthreads();
        *(u16x8*)&sAh[s0r][sc] = a0h; *(u16x8*)&sAl[s0r][sc] = a0l;
        *(u16x8*)&sAh[s1r][sc] = a1h; *(u16x8*)&sAl[s1r][sc] = a1l;
        *(u16x8*)&sBh[s0r][sc] = b0h; *(u16x8*)&sBl[s0r][sc] = b0l;
        *(u16x8*)&sBh[s1r][sc] = b1h; *(u16x8*)&sBl[s1r][sc] = b1l;
        __syncthreads();
        bf16x8 ah[4], al[4], bh[4], bl[4];
#pragma unroll
        for (int i = 0; i < 4; ++i) {
            ah[i] = *(const bf16x8*)&sAh[wm + i * 16 + fr][fk];
            al[i] = *(const bf16x8*)&sAl[wm + i * 16 + fr][fk];
            bh[i] = *(const bf16x8*)&sBh[wn + i * 16 + fr][fk];
            bl[i] = *(const bf16x8*)&sBl[wn + i * 16 + fr][fk];
        }
#pragma unroll
        for (int i = 0; i < 4; ++i)
#pragma unroll
            for (int j = 0; j < 4; ++j) {
                acc[i][j] = __builtin_amdgcn_mfma_f32_16x16x32_bf16(ah[i], bh[j], acc[i][j], 0, 0, 0);
                acc[i][j] = __builtin_amdgcn_mfma_f32_16x16x32_bf16(ah[i], bl[j], acc[i][j], 0, 0, 0);
                acc[i][j] = __builtin_amdgcn_mfma_f32_16x16x32_bf16(al[i], bh[j], acc[i][j], 0, 0, 0);
            }
    }
    const int rq4 = (lane >> 4) * 4;
#pragma unroll
    for (int i = 0; i < 4; ++i) {
        const int rbase = bm + wm + i * 16 + rq4;
#pragma unroll
        for (int j = 0; j < 4; ++j) {
            const int col = bn + wn + j * 16 + fr;
            const float bv = bias ? bias[col] : 0.f;
#pragma unroll
            for (int r = 0; r < 4; ++r) {
                const int row = rbase + r;
                if (row < M) {
                    float v = acc[i][j][r] + bv;
                    if (act == 1) v = fmaxf(v, 0.f);
                    C[(size_t)row * N + col] = v;
                }
            }
        }
    }
}

// ---------------- dual split-K w2 GEMM (fp32): 1020x128x2048, 64x64 tile ----------------
__global__ __launch_bounds__(256) void gemm_w2sk_kernel(
    const float* __restrict__ Ak, const float* __restrict__ Av,
    const float* __restrict__ Bk, const float* __restrict__ Bv,
    float* __restrict__ part) {
    const int pair = blockIdx.z >> 2, ks = blockIdx.z & 3;
    const float* A = pair ? Av : Ak;   // 1020 x 2048
    const float* B = pair ? Bv : Bk;   // 2048 x 128
    __shared__ float As[16][64];
    __shared__ float Bs[16][64];
    const int tid = threadIdx.x;
    const int bm = blockIdx.y * 64, bn = blockIdx.x * 64;
    const int tx = tid & 15, ty = tid >> 4;
    const int ar = tid >> 2, ac = (tid & 3) << 2;
    const int br = tid >> 4, bc = (tid & 15) << 2;
    const int k_lo = ks * 512;
    float acc[4][4] = {};
    for (int k0 = k_lo; k0 < k_lo + 512; k0 += 16) {
        float4 av = make_float4(0.f, 0.f, 0.f, 0.f);
        if (bm + ar < MROWS_) av = *reinterpret_cast<const float4*>(A + (size_t)(bm + ar) * HID_ + k0 + ac);
        float4 bv = *reinterpret_cast<const float4*>(B + (size_t)(k0 + br) * DH_ + bn + bc);
        __syncthreads();
        As[ac + 0][ar] = av.x; As[ac + 1][ar] = av.y; As[ac + 2][ar] = av.z; As[ac + 3][ar] = av.w;
        *reinterpret_cast<float4*>(&Bs[br][bc]) = bv;
        __syncthreads();
#pragma unroll
        for (int k = 0; k < 16; ++k) {
            float4 a = *reinterpret_cast<const float4*>(&As[k][ty << 2]);
            float4 b = *reinterpret_cast<const float4*>(&Bs[k][tx << 2]);
            float aa[4] = {a.x, a.y, a.z, a.w};
            float bb[4] = {b.x, b.y, b.z, b.w};
#pragma unroll
            for (int i = 0; i < 4; ++i)
#pragma unroll
                for (int j = 0; j < 4; ++j) acc[i][j] += aa[i] * bb[j];
        }
        __syncthreads();
    }
    const int row0 = bm + (ty << 2), col0 = bn + (tx << 2);
    float* dst = part + ((size_t)(pair * 4 + ks) * MROWS_) * DH_;
#pragma unroll
    for (int i = 0; i < 4; ++i) {
        int r = row0 + i;
        if (r < MROWS_)
            *reinterpret_cast<float4*>(dst + (size_t)r * DH_ + col0) =
                make_float4(acc[i][0], acc[i][1], acc[i][2], acc[i][3]);
    }
}

// ---------- reduce split-K partials + bias, prepend mem row; emit bf16 hi/lo ----------
// pair=0: ck -> ckh/ckl [kvh][256][128] (key-major). pair=1: cv -> cvth/cvtl [kvh][128][256] (d-major).
__global__ __launch_bounds__(128) void reduce_scatter_kernel(
    const float* __restrict__ part, const float* __restrict__ mem,
    const float* __restrict__ bk, const float* __restrict__ bv,
    u16* __restrict__ ckh, u16* __restrict__ ckl,
    u16* __restrict__ cvth, u16* __restrict__ cvtl) {
    const int r = blockIdx.x, kvh = blockIdx.y, pair = blockIdx.z, d = threadIdx.x;
    float v;
    if (r == 0) {
        v = mem[(size_t)pair * KVH_ * DH_ + kvh * DH_ + d];
    } else {
        const size_t row = (size_t)kvh * NW_ + (r - 1);
        const float* p0 = part + ((size_t)pair * 4 * MROWS_ + row) * DH_ + d;
        const size_t stride = (size_t)MROWS_ * DH_;
        v = p0[0] + p0[stride] + p0[2 * stride] + p0[3 * stride];
        v += (pair ? bv[d] : bk[d]);
    }
    u16 hb = f2bf(v);
    u16 lb = f2bf(v - bf2f(hb));
    if (pair == 0) {
        size_t o = ((size_t)kvh * NWP_ + r) * DH_ + d;
        ckh[o] = hb; ckl[o] = lb;
    } else {
        size_t o = ((size_t)kvh * DH_ + d) * NWP_ + r;
        cvth[o] = hb; cvtl[o] = lb;
    }
}

// ---------------- build compression-MLP inputs (bf16 hi/lo), k and v ----------------
__global__ __launch_bounds__(256) void build_cin_kernel(const float* __restrict__ qkv,
    const float* __restrict__ k_pos, const float* __restrict__ v_pos,
    u16* __restrict__ cink_h, u16* __restrict__ cink_l,
    u16* __restrict__ cinv_h, u16* __restrict__ cinv_l) {
    int w = blockIdx.x, kvh = blockIdx.y, pair = blockIdx.z, tid = threadIdx.x;
    const float* posw = pair ? v_pos : k_pos;
    u16* ch = pair ? cinv_h : cink_h;
    u16* cl = pair ? cinv_l : cink_l;
    const int col_off = pair ? (DIM_ + KVH_ * DH_) : DIM_;
    for (int idx = tid; idx < CBS_ * DH_; idx += 256) {
        int t = idx >> 7, d = idx & 127;
        int srow = w * CST_ + t;
        float v = qkv[(size_t)srow * QKVN_ + col_off + kvh * DH_ + d] + posw[(kvh * CBS_ + t) * DH_ + d];
        size_t o = ((size_t)kvh * NW_ + w) * HID_ + idx;
        u16 hb = f2bf(v);
        ch[o] = hb;
        cl[o] = f2bf(v - bf2f(hb));
    }
}

// ---------------- RoPE for q (16 heads) and k (4 heads) ----------------
__global__ __launch_bounds__(64) void rope_kernel(const float* __restrict__ qkv,
    float* __restrict__ rq, float* __restrict__ rk) {
    int s = blockIdx.x, head = blockIdx.y, i = threadIdx.x;
    float inv = 1.0f / powf(10000.0f, (float)i / 64.0f);
    float ang = (float)s * inv;
    float c = cosf(ang), sn = sinf(ang);
    const float* src; float* dst;
    if (head < HEADS_) {
        src = qkv + (size_t)s * QKVN_ + head * DH_;
        dst = rq + ((size_t)head * S_ + s) * DH_;
    } else {
        int kvh = head - HEADS_;
        src = qkv + (size_t)s * QKVN_ + DIM_ + kvh * DH_;
        dst = rk + ((size_t)kvh * S_ + s) * DH_;
    }
    float t1 = src[2 * i], t2 = src[2 * i + 1];
    dst[2 * i] = t1 * c - t2 * sn;
    dst[2 * i + 1] = t1 * sn + t2 * c;
}

// ------- compression attention via MFMA: 16 queries x 4 g per block + top-k -------
__global__ __launch_bounds__(256) void compattn_mfma_kernel(
    const float* __restrict__ qkv,
    const u16* __restrict__ ckh, const u16* __restrict__ ckl,
    const u16* __restrict__ cvth, const u16* __restrict__ cvtl,
    float* __restrict__ coutb, int* __restrict__ selidx, int* __restrict__ selact) {
    const int s0 = blockIdx.x * 16, kvh = blockIdx.y;
    const int tid = threadIdx.x, lane = tid & 63, w = tid >> 6;
    const int fr = lane & 15, fq = lane >> 4;
    __shared__ u16 attn_h[4][16][264];
    __shared__ u16 attn_l[4][16][264];
    __shared__ float bimpS[16][128];

    // Q fragments: rows = 16 queries, head = kvh*G + w
    bf16x8 qh[4], ql[4];
    {
        const float* qbase = qkv + (size_t)(s0 + fr) * QKVN_ + (kvh * G_ + w) * DH_;
#pragma unroll
        for (int kk = 0; kk < 4; ++kk) {
            int d0 = kk * 32 + fq * 8;
            float4 v0 = *reinterpret_cast<const float4*>(qbase + d0);
            float4 v1 = *reinterpret_cast<const float4*>(qbase + d0 + 4);
            float vv[8] = {v0.x, v0.y, v0.z, v0.w, v1.x, v1.y, v1.z, v1.w};
            u16x8 hh, ll;
#pragma unroll
            for (int j = 0; j < 8; ++j) {
                u16 hb = f2bf(vv[j]);
                hh[j] = hb; ll[j] = f2bf(vv[j] - bf2f(hb));
            }
            qh[kk] = *(bf16x8*)&hh; ql[kk] = *(bf16x8*)&ll;
        }
    }
    // QK^T: 16 column tiles of 16 keys each (256 keys total)
    f32x4 sc[16];
#pragma unroll
    for (int ct = 0; ct < 16; ++ct) {
        f32x4 acc = (f32x4){0.f, 0.f, 0.f, 0.f};
        const u16* kbh = ckh + ((size_t)kvh * NWP_ + ct * 16 + fr) * DH_ + fq * 8;
        const u16* kbl = ckl + ((size_t)kvh * NWP_ + ct * 16 + fr) * DH_ + fq * 8;
#pragma unroll
        for (int kk = 0; kk < 4; ++kk) {
            bf16x8 bh = *(const bf16x8*)(kbh + kk * 32);
            bf16x8 bl = *(const bf16x8*)(kbl + kk * 32);
            acc = __builtin_amdgcn_mfma_f32_16x16x32_bf16(qh[kk], bh, acc, 0, 0, 0);
            acc = __builtin_amdgcn_mfma_f32_16x16x32_bf16(ql[kk], bh, acc, 0, 0, 0);
            acc = __builtin_amdgcn_mfma_f32_16x16x32_bf16(qh[kk], bl, acc, 0, 0, 0);
        }
        sc[ct] = acc;
    }
    // mask + scale + in-register softmax (row = query fq*4+ri; col = ct*16+fr)
    float mrow[4], rsum[4], rinv[4];
#pragma unroll
    for (int ri = 0; ri < 4; ++ri) mrow[ri] = -INFINITY;
#pragma unroll
    for (int ct = 0; ct < 16; ++ct) {
        int j = ct * 16 + fr;
#pragma unroll
        for (int ri = 0; ri < 4; ++ri) {
            int s = s0 + fq * 4 + ri;
            bool vis = (j == 0) || (s > (j - 1) * CST_ + CBS_ - 1);
            float v = vis ? sc[ct][ri] * SCALE_F : -INFINITY;
            sc[ct][ri] = v;
            mrow[ri] = fmaxf(mrow[ri], v);
        }
    }
#pragma unroll
    for (int off = 8; off >= 1; off >>= 1)
#pragma unroll
        for (int ri = 0; ri < 4; ++ri) mrow[ri] = fmaxf(mrow[ri], __shfl_xor(mrow[ri], off));
#pragma unroll
    for (int ri = 0; ri < 4; ++ri) rsum[ri] = 0.f;
#pragma unroll
    for (int ct = 0; ct < 16; ++ct)
#pragma unroll
        for (int ri = 0; ri < 4; ++ri) {
            float e = expf(sc[ct][ri] - mrow[ri]);
            sc[ct][ri] = e; rsum[ri] += e;
        }
#pragma unroll
    for (int off = 8; off >= 1; off >>= 1)
#pragma unroll
        for (int ri = 0; ri < 4; ++ri) rsum[ri] += __shfl_xor(rsum[ri], off);
#pragma unroll
    for (int ri = 0; ri < 4; ++ri) rinv[ri] = 1.f / rsum[ri];
    // attn -> LDS (bf16 hi/lo)
#pragma unroll
    for (int ct = 0; ct < 16; ++ct)
#pragma unroll
        for (int ri = 0; ri < 4; ++ri) {
            float a = sc[ct][ri] * rinv[ri];
            u16 hb = f2bf(a);
            attn_h[w][fq * 4 + ri][ct * 16 + fr] = hb;
            attn_l[w][fq * 4 + ri][ct * 16 + fr] = f2bf(a - bf2f(hb));
        }
    __syncthreads();
    // block importance: bimp[sq][f] = (1/8) * sum_g (attn[2f+1] + attn[2f+2])
    for (int idx = tid; idx < 16 * 128; idx += 256) {
        int sq = idx >> 7, f = idx & 127;
        int j1 = 2 * f + 1, j2 = 2 * f + 2;
        float a = 0.f;
#pragma unroll
        for (int g = 0; g < 4; ++g) {
            a += bf2f(attn_h[g][sq][j1]) + bf2f(attn_l[g][sq][j1]);
            if (f < 127) a += bf2f(attn_h[g][sq][j2]) + bf2f(attn_l[g][sq][j2]);
        }
        float v = a * 0.125f;
        bimpS[sq][f] = (f < (s0 >> 4)) ? v : -1.0f;
    }
    __syncthreads();
    // serial top-4 per query (strict >, lowest index wins)
    if (tid < 16) {
        int s = s0 + tid;
        int base = (kvh * S_ + s) * NSEL_;
        for (int kk = 0; kk < NSEL_; ++kk) {
            float best = -1e30f; int bi = 0;
            for (int f = 0; f < NF_; ++f) {
                float v = bimpS[tid][f];
                if (v > best) { best = v; bi = f; }
            }
            bimpS[tid][bi] = -1e31f;
            selidx[base + kk] = bi;
            selact[base + kk] = (best > 0.f) ? 1 : 0;
        }
    }
    // PV: out[16 x 128] = attn[16 x 256] @ cv[256 x 128] (cv stored d-major)
    f32x4 po[8];
#pragma unroll
    for (int dt = 0; dt < 8; ++dt) po[dt] = (f32x4){0.f, 0.f, 0.f, 0.f};
#pragma unroll
    for (int jc = 0; jc < 8; ++jc) {
        bf16x8 ah = *(const bf16x8*)&attn_h[w][fr][jc * 32 + fq * 8];
        bf16x8 al = *(const bf16x8*)&attn_l[w][fr][jc * 32 + fq * 8];
#pragma unroll
        for (int dt = 0; dt < 8; ++dt) {
            const u16* vbh = cvth + ((size_t)kvh * DH_ + dt * 16 + fr) * NWP_ + jc * 32 + fq * 8;
            const u16* vbl = cvtl + ((size_t)kvh * DH_ + dt * 16 + fr) * NWP_ + jc * 32 + fq * 8;
            bf16x8 bh = *(const bf16x8*)vbh;
            bf16x8 bl = *(const bf16x8*)vbl;
            po[dt] = __builtin_amdgcn_mfma_f32_16x16x32_bf16(ah, bh, po[dt], 0, 0, 0);
            po[dt] = __builtin_amdgcn_mfma_f32_16x16x32_bf16(al, bh, po[dt], 0, 0, 0);
            po[dt] = __builtin_amdgcn_mfma_f32_16x16x32_bf16(ah, bl, po[dt], 0, 0, 0);
        }
    }
#pragma unroll
    for (int dt = 0; dt < 8; ++dt)
#pragma unroll
        for (int ri = 0; ri < 4; ++ri) {
            int sq = fq * 4 + ri;
            coutb[(((size_t)(kvh * G_ + w)) * S_ + s0 + sq) * DH_ + dt * 16 + fr] = po[dt][ri];
        }
}

// ---------------- selection attention (J = 80 keys), split-dot + LDS-staged V ----------------
__global__ __launch_bounds__(256) void selattn_kernel(
    const float* __restrict__ rq, const float* __restrict__ rk, const float* __restrict__ qkv,
    const int* __restrict__ selidx, const int* __restrict__ selact, float* __restrict__ foutb) {
    const int s = blockIdx.x, kvh = blockIdx.y, tid = threadIdx.x;
    const int J = (NSEL_ + 1) * SBS_;  // 80
    __shared__ float qs[G_][DH_];
    __shared__ float kl[80][DH_ + 1];  // phase 1: K_sel, phase 2: V_sel
    __shared__ float sc[G_][80];
    __shared__ int posb[80];
    __shared__ int maskb[80];
    if (tid < J) {
        int b = tid >> 4, t = tid & 15;
        int p, ok;
        if (b < NSEL_) {
            int base = (kvh * S_ + s) * NSEL_ + b;
            int f = selidx[base];
            p = f * SBS_ + t;
            ok = selact[base] && (p <= s);
        } else {
            p = (s >> 4) * SBS_ + t;
            ok = (p <= s);
        }
        posb[tid] = p; maskb[tid] = ok;
    }
    for (int idx = tid; idx < G_ * DH_; idx += 256) {
        int g = idx >> 7, d = idx & 127;
        qs[g][d] = rq[(((size_t)(kvh * G_ + g)) * S_ + s) * DH_ + d];
    }
    __syncthreads();
    for (int idx = tid; idx < J * DH_; idx += 256) {
        int r = idx >> 7, d = idx & 127;
        kl[r][d] = rk[((size_t)kvh * S_ + posb[r]) * DH_ + d];
    }
    __syncthreads();
    // scores: each dot split across 4 lanes (32-FMA partials + shfl combine)
    for (int t = tid; t < G_ * J * 4; t += 256) {
        int q4 = t & 3;
        int rest = t >> 2;
        int g = rest / J, j = rest % J;
        const float* qp = &qs[g][q4 * 32];
        const float* kp = &kl[j][q4 * 32];
        float a = 0.f;
#pragma unroll
        for (int d = 0; d < 32; ++d) a += qp[d] * kp[d];
        a += __shfl_xor(a, 1);
        a += __shfl_xor(a, 2);
        if (q4 == 0) sc[g][j] = maskb[j] ? a * SCALE_F : -INFINITY;
    }
    __syncthreads();
    const int wv = tid >> 6, ln = tid & 63;
    float v0 = sc[wv][ln];
    float v1 = (ln < J - 64) ? sc[wv][64 + ln] : -INFINITY;
    float m = fmaxf(v0, v1);
#pragma unroll
    for (int off = 32; off > 0; off >>= 1) m = fmaxf(m, __shfl_xor(m, off));
    float e0 = expf(v0 - m);
    float e1 = (ln < J - 64) ? expf(v1 - m) : 0.f;
    float ssum = e0 + e1;
#pragma unroll
    for (int off = 32; off > 0; off >>= 1) ssum += __shfl_xor(ssum, off);
    float inv = 1.f / ssum;
    sc[wv][ln] = e0 * inv;
    if (ln < J - 64) sc[wv][64 + ln] = e1 * inv;
    __syncthreads();
    // stage V_sel into the dead K buffer
    for (int idx = tid; idx < J * DH_; idx += 256) {
        int r = idx >> 7, d = idx & 127;
        kl[r][d] = qkv[(size_t)posb[r] * QKVN_ + (DIM_ + KVH_ * DH_) + kvh * DH_ + d];
    }
    __syncthreads();
    for (int it = tid; it < G_ * DH_; it += 256) {
        int g = it >> 7, d = it & 127;
        float a = 0.f;
#pragma unroll 8
        for (int j = 0; j < J; ++j) a += sc[g][j] * kl[j][d];
        foutb[(((size_t)(kvh * G_ + g)) * S_ + s) * DH_ + d] = a;
    }
}

// ---------------- sliding window attention (J = 65 keys), split-dot + LDS-staged V ----------------
__global__ __launch_bounds__(256) void swattn_kernel(
    const float* __restrict__ rq, const float* __restrict__ rk, const float* __restrict__ qkv,
    float* __restrict__ swoutb) {
    const int s = blockIdx.x, kvh = blockIdx.y, tid = threadIdx.x;
    const int J = SW_ + 1;  // 65
    __shared__ float qs[G_][DH_];
    __shared__ float kl[65][DH_ + 1];  // phase 1: K, phase 2: V
    __shared__ float sc[G_][65];
    for (int idx = tid; idx < G_ * DH_; idx += 256) {
        int g = idx >> 7, d = idx & 127;
        qs[g][d] = rq[(((size_t)(kvh * G_ + g)) * S_ + s) * DH_ + d];
    }
    for (int idx = tid; idx < J * DH_; idx += 256) {
        int r = idx >> 7, d = idx & 127;
        int p = s - SW_ + r;
        kl[r][d] = (p >= 0) ? rk[((size_t)kvh * S_ + p) * DH_ + d] : 0.f;
    }
    __syncthreads();
    // scores: split each 128-dot across 4 lanes
    for (int t = tid; t < G_ * J * 4; t += 256) {
        int q4 = t & 3;
        int rest = t >> 2;
        int g = rest / J, j = rest % J;
        const float* qp = &qs[g][q4 * 32];
        const float* kp = &kl[j][q4 * 32];
        float a = 0.f;
#pragma unroll
        for (int d = 0; d < 32; ++d) a += qp[d] * kp[d];
        a += __shfl_xor(a, 1);
        a += __shfl_xor(a, 2);
        if (q4 == 0) {
            int p = s - SW_ + j;
            sc[g][j] = (p >= 0) ? a * SCALE_F : -INFINITY;
        }
    }
    __syncthreads();
    const int wv = tid >> 6, ln = tid & 63;
    float v0 = sc[wv][ln];
    float v1 = (ln < J - 64) ? sc[wv][64 + ln] : -INFINITY;
    float m = fmaxf(v0, v1);
#pragma unroll
    for (int off = 32; off > 0; off >>= 1) m = fmaxf(m, __shfl_xor(m, off));
    float e0 = expf(v0 - m);
    float e1 = (ln < J - 64) ? expf(v1 - m) : 0.f;
    float ssum = e0 + e1;
#pragma unroll
    for (int off = 32; off > 0; off >>= 1) ssum += __shfl_xor(ssum, off);
    float inv = 1.f / ssum;
    sc[wv][ln] = e0 * inv;
    if (ln < J - 64) sc[wv][64 + ln] = e1 * inv;
    __syncthreads();
    // stage V into the dead K buffer (clamped row for p<0; weight is 0 there)
    for (int idx = tid; idx < J * DH_; idx += 256) {
        int r = idx >> 7, d = idx & 127;
        int p = s - SW_ + r;
        int pc = p < 0 ? 0 : p;
        kl[r][d] = qkv[(size_t)pc * QKVN_ + (DIM_ + KVH_ * DH_) + kvh * DH_ + d];
    }
    __syncthreads();
    for (int it = tid; it < G_ * DH_; it += 256) {
        int g = it >> 7, d = it & 127;
        float a = 0.f;
#pragma unroll 8
        for (int j = 0; j < J; ++j) a += sc[g][j] * kl[j][d];
        swoutb[(((size_t)(kvh * G_ + g)) * S_ + s) * DH_ + d] = a;
    }
}

// ---------------- gating head v2: coalesced flat-w decomposition ----------------
// Block = 8 s-rows. w_comb read as coalesced float4 (48 = 4*12: float4 never crosses a row).
// For j = k mod 3, the output col-group (tid + 4j) mod 12 is k-invariant -> 3 float4 accs/row.
__global__ __launch_bounds__(256) void comb_kernel(const float* __restrict__ h,
    const float* __restrict__ w_comb, const float* __restrict__ b_comb, float* __restrict__ comb) {
    const int s0 = blockIdx.x * 8, tid = threadIdx.x;
    __shared__ float hs[8][DIM_];      // 64 KB
    __shared__ float4 part[256][3];    // 12 KB
    for (int idx = tid; idx < 8 * (DIM_ / 4); idx += 256) {
        int r = idx >> 9, c4 = idx & 511;
        reinterpret_cast<float4*>(hs[r])[c4] =
            reinterpret_cast<const float4*>(h + (size_t)(s0 + r) * DIM_)[c4];
    }
    __syncthreads();
    float4 a[8][3];
#pragma unroll
    for (int r = 0; r < 8; ++r)
#pragma unroll
        for (int j = 0; j < 3; ++j) a[r][j] = make_float4(0.f, 0.f, 0.f, 0.f);
    const float4* w4p = reinterpret_cast<const float4*>(w_comb);
    for (int kk = 0; kk < 32; ++kk) {
#pragma unroll
        for (int j = 0; j < 3; ++j) {
            int idx4 = tid + (kk * 3 + j) * 256;
            int d = idx4 / 12;
            float4 w4 = w4p[idx4];
#pragma unroll
            for (int r = 0; r < 8; ++r) {
                float hv = hs[r][d];
                a[r][j].x += hv * w4.x;
                a[r][j].y += hv * w4.y;
                a[r][j].z += hv * w4.z;
                a[r][j].w += hv * w4.w;
            }
        }
    }
    // reduce: output col c gets contributions from (t, j) with (t + 4j) mod 12 == c/4
    for (int r = 0; r < 8; ++r) {
#pragma unroll
        for (int j = 0; j < 3; ++j) part[tid][j] = a[r][j];
        __syncthreads();
        if (tid < 48) {
            int og = tid >> 2, l = tid & 3;
            float sum = 0.f;
#pragma unroll
            for (int j = 0; j < 3; ++j) {
                int r12 = (og - 4 * j) % 12;
                if (r12 < 0) r12 += 12;
                int cnt = (r12 <= 3) ? 22 : 21;
                for (int m = 0; m < cnt; ++m) {
                    const float* p = reinterpret_cast<const float*>(&part[r12 + 12 * m][j]);
                    sum += p[l];
                }
            }
            comb[(size_t)(s0 + r) * 48 + tid] = 1.f / (1.f + expf(-(sum + b_comb[tid])));
        }
        __syncthreads();
    }
}

// ---------------- combine branches with gates -> bf16 hi/lo ----------------
__global__ __launch_bounds__(256) void combine_kernel(const float* __restrict__ c0b,
    const float* __restrict__ c1b, const float* __restrict__ c2b,
    const float* __restrict__ comb, u16* __restrict__ comb_h, u16* __restrict__ comb_l) {
    size_t i = (size_t)blockIdx.x * 256 + threadIdx.x;
    int s = (int)(i >> 11);
    int hd = (int)(i & 2047);
    int hh = hd >> 7;
    int d = hd & 127;
    size_t src = ((size_t)hh * S_ + s) * DH_ + d;
    const float* cb = comb + (size_t)s * 48 + hh * 3;
    float v = c0b[src] * cb[0] + c1b[src] * cb[1] + c2b[src] * cb[2];
    u16 hb = f2bf(v);
    comb_h[i] = hb;
    comb_l[i] = f2bf(v - bf2f(hb));
}

extern "C" void kernel_launch(void* const* d_in, const int* in_sizes, int n_in,
                              void* d_out, int out_size, void* d_ws, size_t ws_size,
                              hipStream_t stream) {
    const float* x      = (const float*)d_in[0];
    const float* g_norm = (const float*)d_in[1];
    const float* w_qkv  = (const float*)d_in[2];
    const float* k_pos  = (const float*)d_in[3];
    const float* v_pos  = (const float*)d_in[4];
    const float* mem_kv = (const float*)d_in[5];
    const float* kc_w1  = (const float*)d_in[6];
    const float* kc_b1  = (const float*)d_in[7];
    const float* kc_w2  = (const float*)d_in[8];
    const float* kc_b2  = (const float*)d_in[9];
    const float* vc_w1  = (const float*)d_in[10];
    const float* vc_b1  = (const float*)d_in[11];
    const float* vc_w2  = (const float*)d_in[12];
    const float* vc_b2  = (const float*)d_in[13];
    const float* w_comb = (const float*)d_in[14];
    const float* b_comb = (const float*)d_in[15];
    const float* w_out  = (const float*)d_in[16];
    float* out = (float*)d_out;
    float* ws = (float*)d_ws;

    // Persistent: h(4194304) qkv(6291456) + compressed-kv bf16 arrays (262144 fl worth)
    float* h   = ws;
    float* qkv = h + 4194304;
    u16* ckh  = (u16*)(qkv + 6291456);   // 131,072 u16 each
    u16* ckl  = ckh + 131072;
    u16* cvth = ckl + 131072;
    u16* cvtl = cvth + 131072;
    float* uni = qkv + 6291456 + 262144; // union region, 3 sequential layouts

    // Layout X (steps 1-2): h splits + transposed/split w_qkv
    u16* h_hi    = (u16*)uni;            // 4,194,304 u16
    u16* h_lo    = h_hi + 4194304;
    u16* wqkvt_h = h_lo + 4194304;       // 6,291,456 u16
    u16* wqkvt_l = wqkvt_h + 6291456;

    // Layout A (steps 3-6): w1 transposes + cin splits + chid + part
    u16* w1kt_h = (u16*)uni;             // 4,194,304 u16 each
    u16* w1kt_l = w1kt_h + 4194304;
    u16* w1vt_h = w1kt_l + 4194304;
    u16* w1vt_l = w1vt_h + 4194304;
    u16* cink_h = w1vt_l + 4194304;      // 2,088,960 u16 each
    u16* cink_l = cink_h + 2088960;
    u16* cinv_h = cink_l + 2088960;
    u16* cinv_l = cinv_h + 2088960;
    float* chid_k = uni + 12566528;      // 2,088,960 fl each
    float* chid_v = chid_k + 2088960;
    float* part   = chid_v + 2088960;    // 1,044,480 fl

    // Layout B (steps 7+): attention buffers
    float* rq     = uni;                 // 4,194,304
    float* rk     = rq + 4194304;        // 1,048,576
    float* coutb  = rk + 1048576;        // 4,194,304 (aliased by woutt after combine)
    float* foutb  = coutb + 4194304;     // 4,194,304
    float* swoutb = foutb + 4194304;     // 4,194,304
    float* combb  = swoutb + 4194304;    // 98,304
    u16* comb_h   = (u16*)(combb + 98304);      // 4,194,304 u16
    u16* comb_l   = comb_h + 4194304;           // 4,194,304 u16
    int* selidx   = (int*)(comb_l + 4194304);   // 32,768 ints
    int* selact   = selidx + 32768;             // 32,768 ints
    u16* woutt_h  = (u16*)coutb;         // 4,194,304 u16 each (fits in dead coutb)
    u16* woutt_l  = woutt_h + 4194304;

    // 1) RMSNorm + h split
    rmsnorm_kernel<<<S_, 256, 0, stream>>>(x, g_norm, h, h_hi, h_lo);
    // 2) split/transpose w_qkv, then qkv projection via bf16x3 MFMA
    tsplit_kernel<<<dim3(QKVN_ / 32, DIM_ / 32), 256, 0, stream>>>(w_qkv, wqkvt_h, wqkvt_l, DIM_, QKVN_);
    gemm_mfma_kernel<<<dim3(QKVN_ / 128, S_ / 128, 1), 256, 0, stream>>>(
        h_hi, h_lo, wqkvt_h, wqkvt_l, qkv, nullptr,
        h_hi, h_lo, wqkvt_h, wqkvt_l, qkv, nullptr, S_, QKVN_, DIM_, 0);
    // 3) w1 transposes (Layout A; X is dead now)
    tsplit_kernel<<<dim3(HID_ / 32, HID_ / 32), 256, 0, stream>>>(kc_w1, w1kt_h, w1kt_l, HID_, HID_);
    tsplit_kernel<<<dim3(HID_ / 32, HID_ / 32), 256, 0, stream>>>(vc_w1, w1vt_h, w1vt_l, HID_, HID_);
    // 4) compression MLP inputs (bf16 hi/lo)
    build_cin_kernel<<<dim3(NW_, KVH_, 2), 256, 0, stream>>>(qkv, k_pos, v_pos,
        cink_h, cink_l, cinv_h, cinv_l);
    // 5) w1 (relu+bias), dual bf16x3 MFMA -> chid fp32
    gemm_mfma_kernel<<<dim3(HID_ / 128, 8, 2), 256, 0, stream>>>(
        cink_h, cink_l, w1kt_h, w1kt_l, chid_k, kc_b1,
        cinv_h, cinv_l, w1vt_h, w1vt_l, chid_v, vc_b1, MROWS_, HID_, HID_, 1);
    // 6) w2 fp32 split-K + reduce/prepend -> bf16 hi/lo compressed K (key-major) / V (d-major)
    gemm_w2sk_kernel<<<dim3(DH_ / 64, 16, 8), 256, 0, stream>>>(chid_k, chid_v, kc_w2, vc_w2, part);
    reduce_scatter_kernel<<<dim3(NWP_, KVH_, 2), 128, 0, stream>>>(part, mem_kv, kc_b2, vc_b2,
        ckh, ckl, cvth, cvtl);
    // 7) RoPE (Layout B; A is dead now)
    rope_kernel<<<dim3(S_, HEADS_ + KVH_), 64, 0, stream>>>(qkv, rq, rk);
    // 8) attention branches
    compattn_mfma_kernel<<<dim3(S_ / 16, KVH_), 256, 0, stream>>>(qkv, ckh, ckl, cvth, cvtl,
        coutb, selidx, selact);
    selattn_kernel<<<dim3(S_, KVH_), 256, 0, stream>>>(rq, rk, qkv, selidx, selact, foutb);
    swattn_kernel<<<dim3(S_, KVH_), 256, 0, stream>>>(rq, rk, qkv, swoutb);
    // 9) gating + combine (writes bf16 hi/lo of combined)
    comb_kernel<<<S_ / 8, 256, 0, stream>>>(h, w_comb, b_comb, combb);
    combine_kernel<<<(S_ * DIM_) / 256, 256, 0, stream>>>(coutb, foutb, swoutb, combb, comb_h, comb_l);
    // 10) split/transpose w_out (aliases dead coutb), then output projection
    tsplit_kernel<<<dim3(DIM_ / 32, DIM_ / 32), 256, 0, stream>>>(w_out, woutt_h, woutt_l, HEADS_ * DH_, DIM_);
    gemm_mfma_kernel<<<dim3(DIM_ / 128, S_ / 128, 1), 256, 0, stream>>>(
        comb_h, comb_l, woutt_h, woutt_l, out, nullptr,
        comb_h, comb_l, woutt_h, woutt_l, out, nullptr, S_, DIM_, HEADS_ * DH_, 0);
}